// Round 2
// baseline (1067.261 us; speedup 1.0000x reference)
//
#include <hip/hip_runtime.h>
#include <hip/hip_bf16.h>
#include <float.h>

#define GG    64
#define NPG   1024
#define EPG   8192      // edges per graph
#define NE    524288
#define FIN   128
#define HID   256
#define K1    512
#define K2    256
#define NN0   65536     // GG*NPG
#define NN1   32768     // GG*K1
#define NN2   16384     // GG*K2
#define EPSBN 1e-5f

__device__ __forceinline__ float gelu_exact(float v) {
    return 0.5f * v * (1.0f + erff(v * 0.7071067811865476f));
}

// ---------- small prep kernels ----------
__global__ __launch_bounds__(256) void k_w1cat(const float* __restrict__ Wrel,
        const float* __restrict__ Wroot, float* __restrict__ Wc) {
    const int i = blockIdx.x * 256 + threadIdx.x;       // 65536 = 256x256
    const int k = i >> 8, n = i & 255;
    Wc[i] = (k < FIN) ? Wrel[k * HID + n] : Wroot[(k - FIN) * HID + n];
}

__global__ __launch_bounds__(256) void k_w2cat(const float* __restrict__ Wrel,
        const float* __restrict__ Wroot, float* __restrict__ Wc) {
    const int i = blockIdx.x * 256 + threadIdx.x;       // 131072 = 512x256
    const int k = i >> 8, n = i & 255;
    Wc[i] = (k < HID) ? Wrel[k * HID + n] : Wroot[(k - HID) * HID + n];
}

__global__ __launch_bounds__(256) void k_q2norm(const float* __restrict__ p2,
        float* __restrict__ q2) {
    __shared__ float red[256];
    const int c = threadIdx.x;
    const float pv = p2[c];
    red[c] = pv * pv;
    __syncthreads();
    for (int s = 128; s > 0; s >>= 1) {
        if (c < s) red[c] += red[c + s];
        __syncthreads();
    }
    q2[c] = pv * rsqrtf(red[0]);
}

__global__ __launch_bounds__(256) void k_copy_x(const float* __restrict__ x,
        float* __restrict__ A1) {
    const int total = NN0 * (FIN / 4);                  // float4 count
    for (int i = blockIdx.x * 256 + threadIdx.x; i < total; i += gridDim.x * 256) {
        const int r = i >> 5, c4 = i & 31;
        reinterpret_cast<float4*>(A1)[(size_t)r * 64 + 32 + c4] =
            reinterpret_cast<const float4*>(x)[i];
    }
}

// ---------- aggregation: LDS-staged gather + LDS-atomic scatter ----------
// grid 512: 64 graphs x 8 chunks of 16 cols. XCD swizzle keeps one graph's
// chunks (shared src/dst + shared x cache lines) on one XCD's L2.
__global__ __launch_bounds__(512) void k_agg1(const float* __restrict__ x,
        const int* __restrict__ src, const int* __restrict__ dst,
        float* __restrict__ A1) {
    __shared__ float xs[NPG * 16];          // 64 KB staged source cols
    __shared__ float acc[NPG * 16];         // 64 KB accumulator
    __shared__ int   es[2048];              // 8 KB edge tile
    __shared__ int   ed[2048];              // 8 KB
    const int b = blockIdx.x;
    const int g = ((b & 7) << 3) | ((b >> 3) & 7);  // XCD-grouped graph id
    const int ch = b >> 6;                           // 0..7
    const int c0 = ch << 4;
    const int tid = threadIdx.x;
    const float4* x4 = reinterpret_cast<const float4*>(x);
    for (int i = tid; i < NPG * 4; i += 512) {       // stage 16 cols, coalesced
        const int row = i >> 2, q = i & 3;
        reinterpret_cast<float4*>(xs)[i] =
            x4[(size_t)((g << 10) + row) * 32 + (c0 >> 2) + q];
    }
    for (int i = tid; i < NPG * 16; i += 512) acc[i] = 0.f;
    const int f = tid & 15, sub = tid >> 4;          // 32 parallel edge slots
    const int ebase = g * EPG;
    for (int t0 = 0; t0 < EPG; t0 += 2048) {
        __syncthreads();
        for (int i = tid; i < 2048; i += 512) {
            es[i] = src[ebase + t0 + i] & (NPG - 1);
            ed[i] = dst[ebase + t0 + i] & (NPG - 1);
        }
        __syncthreads();
        for (int eb = sub; eb < 2048; eb += 32) {
            unsafeAtomicAdd(&acc[(ed[eb] << 4) + f], xs[(es[eb] << 4) + f]);
        }
    }
    __syncthreads();
    for (int i = tid; i < NPG * 4; i += 512) {
        const int row = i >> 2, q = i & 3;
        reinterpret_cast<float4*>(A1)[(size_t)((g << 10) + row) * 64 + (c0 >> 2) + q] =
            reinterpret_cast<float4*>(acc)[i];
    }
}

// grid 512: 64 graphs x 8 chunks of 32 cols. Reads A2 right half (cols
// 256..511), writes A2 left half (cols 0..255) — disjoint, no hazard.
__global__ __launch_bounds__(512) void k_agg2(const float* __restrict__ A2r,
        const int* __restrict__ ns, const int* __restrict__ nd,
        float* __restrict__ A2w) {
    __shared__ float xs[K1 * 32];           // 64 KB
    __shared__ float acc[K1 * 32];          // 64 KB
    __shared__ int   es[2048];
    __shared__ int   ed[2048];
    const int b = blockIdx.x;
    const int g = ((b & 7) << 3) | ((b >> 3) & 7);
    const int ch = b >> 6;                           // 0..7
    const int c0 = ch << 5;
    const int tid = threadIdx.x;
    const float4* s4 = reinterpret_cast<const float4*>(A2r);
    for (int i = tid; i < K1 * 8; i += 512) {        // stage 32 cols from right half
        const int row = i >> 3, q = i & 7;
        reinterpret_cast<float4*>(xs)[i] =
            s4[(size_t)((g << 9) + row) * 128 + 64 + (c0 >> 2) + q];
    }
    for (int i = tid; i < K1 * 32; i += 512) acc[i] = 0.f;
    const int f = tid & 31, sub = tid >> 5;          // 16 parallel edge slots
    const int ebase = g * EPG;
    for (int t0 = 0; t0 < EPG; t0 += 2048) {
        __syncthreads();
        for (int i = tid; i < 2048; i += 512) {
            es[i] = ns[ebase + t0 + i];
            ed[i] = nd[ebase + t0 + i];
        }
        __syncthreads();
        for (int eb = sub; eb < 2048; eb += 16) {
            const int s = es[eb];
            if (s < 0) continue;
            unsafeAtomicAdd(&acc[((ed[eb] & (K1 - 1)) << 5) + f],
                            xs[((s & (K1 - 1)) << 5) + f]);
        }
    }
    __syncthreads();
    for (int i = tid; i < K1 * 8; i += 512) {
        const int row = i >> 3, q = i & 7;
        reinterpret_cast<float4*>(A2w)[(size_t)((g << 9) + row) * 128 + (c0 >> 2) + q] =
            reinterpret_cast<float4*>(acc)[i];
    }
}

// ---------- fp32 SGEMM, 128x128 tile, optional gelu+BN-stats epilogue ----------
template<int EPI>   // 0: +bias; 1: +bias, gelu, column sum/sumsq stats
__global__ __launch_bounds__(256) void k_gemm128(
        const float* __restrict__ A, const float* __restrict__ B,
        const float* __restrict__ bias, float* __restrict__ C,
        float* __restrict__ stats, int M, int K, int N) {
    __shared__ float As[16][128];
    __shared__ float Bs[16][128];
    __shared__ float csum[128];
    __shared__ float csq[128];
    const int tid = threadIdx.x;
    const int tx = tid & 15, ty = tid >> 4;
    const int m0 = blockIdx.x * 128, n0 = blockIdx.y * 128;

    float acc[8][8];
#pragma unroll
    for (int i = 0; i < 8; ++i)
#pragma unroll
        for (int j = 0; j < 8; ++j) acc[i][j] = 0.f;

    const int ar = tid >> 2, akc = (tid & 3) << 2;
    const int bkr = tid >> 4, bnc = (tid & 15) << 3;

    for (int k0 = 0; k0 < K; k0 += 16) {
        const float4 a0 = *reinterpret_cast<const float4*>(A + (size_t)(m0 + ar) * K + k0 + akc);
        const float4 a1 = *reinterpret_cast<const float4*>(A + (size_t)(m0 + ar + 64) * K + k0 + akc);
        const float4 b0 = *reinterpret_cast<const float4*>(B + (size_t)(k0 + bkr) * N + n0 + bnc);
        const float4 b1 = *reinterpret_cast<const float4*>(B + (size_t)(k0 + bkr) * N + n0 + bnc + 4);
        __syncthreads();
        As[akc + 0][ar] = a0.x; As[akc + 1][ar] = a0.y; As[akc + 2][ar] = a0.z; As[akc + 3][ar] = a0.w;
        As[akc + 0][ar + 64] = a1.x; As[akc + 1][ar + 64] = a1.y; As[akc + 2][ar + 64] = a1.z; As[akc + 3][ar + 64] = a1.w;
        *reinterpret_cast<float4*>(&Bs[bkr][bnc]) = b0;
        *reinterpret_cast<float4*>(&Bs[bkr][bnc + 4]) = b1;
        __syncthreads();
#pragma unroll
        for (int k = 0; k < 16; ++k) {
            const float4 av0 = *reinterpret_cast<const float4*>(&As[k][ty << 2]);
            const float4 av1 = *reinterpret_cast<const float4*>(&As[k][64 + (ty << 2)]);
            const float4 bv0 = *reinterpret_cast<const float4*>(&Bs[k][tx << 2]);
            const float4 bv1 = *reinterpret_cast<const float4*>(&Bs[k][64 + (tx << 2)]);
            const float a[8] = {av0.x, av0.y, av0.z, av0.w, av1.x, av1.y, av1.z, av1.w};
            const float b[8] = {bv0.x, bv0.y, bv0.z, bv0.w, bv1.x, bv1.y, bv1.z, bv1.w};
#pragma unroll
            for (int i = 0; i < 8; ++i)
#pragma unroll
                for (int j = 0; j < 8; ++j) acc[i][j] = fmaf(a[i], b[j], acc[i][j]);
        }
    }

    if (EPI == 1) {
        if (tid < 128) { csum[tid] = 0.f; csq[tid] = 0.f; }
        __syncthreads();
    }

    const float4 bia0 = *reinterpret_cast<const float4*>(bias + n0 + (tx << 2));
    const float4 bia1 = *reinterpret_cast<const float4*>(bias + n0 + 64 + (tx << 2));
    const float bcol[8] = {bia0.x, bia0.y, bia0.z, bia0.w, bia1.x, bia1.y, bia1.z, bia1.w};
    float sArr[8] = {0, 0, 0, 0, 0, 0, 0, 0};
    float qArr[8] = {0, 0, 0, 0, 0, 0, 0, 0};

#pragma unroll
    for (int i = 0; i < 8; ++i) {
        const int row = m0 + ((i < 4) ? ((ty << 2) + i) : (64 + (ty << 2) + i - 4));
        float v[8];
#pragma unroll
        for (int j = 0; j < 8; ++j) {
            float t = acc[i][j] + bcol[j];
            if (EPI == 1) {
                t = gelu_exact(t);
                sArr[j] += t;
                qArr[j] += t * t;
            }
            v[j] = t;
        }
        *reinterpret_cast<float4*>(C + (size_t)row * N + n0 + (tx << 2)) =
            make_float4(v[0], v[1], v[2], v[3]);
        *reinterpret_cast<float4*>(C + (size_t)row * N + n0 + 64 + (tx << 2)) =
            make_float4(v[4], v[5], v[6], v[7]);
    }
    if (EPI == 1) {
#pragma unroll
        for (int j = 0; j < 8; ++j) {
            const int cl = (j < 4) ? ((tx << 2) + j) : (64 + (tx << 2) + j - 4);
            unsafeAtomicAdd(&csum[cl], sArr[j]);
            unsafeAtomicAdd(&csq[cl], qArr[j]);
        }
        __syncthreads();
        if (tid < 128) {
            unsafeAtomicAdd(&stats[n0 + tid], csum[tid]);
            unsafeAtomicAdd(&stats[HID + n0 + tid], csq[tid]);
        }
    }
}

// ---------- BN finalize / score fold ----------
__global__ __launch_bounds__(256) void k_finalize1(const float* __restrict__ stats,
        const float* __restrict__ g1, const float* __restrict__ bt1,
        const float* __restrict__ p1, float* __restrict__ scale,
        float* __restrict__ shift, float* __restrict__ q, float* __restrict__ r) {
    __shared__ float red[256];
    const int c = threadIdx.x;
    const float m = stats[c] * (1.f / NN0);
    const float v = stats[HID + c] * (1.f / NN0) - m * m;
    const float sc = g1[c] * rsqrtf(v + EPSBN);
    const float sh = bt1[c] - m * sc;
    scale[c] = sc;
    shift[c] = sh;
    const float pv = p1[c];
    red[c] = pv * pv;
    __syncthreads();
    for (int s = 128; s > 0; s >>= 1) {
        if (c < s) red[c] += red[c + s];
        __syncthreads();
    }
    const float inv = rsqrtf(red[0]);
    q[c] = sc * pv * inv;
    __syncthreads();
    red[c] = sh * pv * inv;
    __syncthreads();
    for (int s = 128; s > 0; s >>= 1) {
        if (c < s) red[c] += red[c + s];
        __syncthreads();
    }
    if (c == 0) r[0] = red[0];
}

__global__ __launch_bounds__(256) void k_finalize2(const float* __restrict__ stats,
        const float* __restrict__ g2, const float* __restrict__ bt2,
        float* __restrict__ scale, float* __restrict__ shift) {
    const int c = threadIdx.x;
    const float m = stats[c] * (1.f / NN1);
    const float v = stats[HID + c] * (1.f / NN1) - m * m;
    const float sc = g2[c] * rsqrtf(v + EPSBN);
    scale[c] = sc;
    shift[c] = bt2[c] - m * sc;
}

// ---------- scores: tanh(h . q + r), one wave per node ----------
__global__ __launch_bounds__(256) void k_score(const float* __restrict__ H,
        const float* __restrict__ q, const float* __restrict__ r,
        float* __restrict__ out) {
    const int node = blockIdx.x * 4 + (threadIdx.x >> 6);
    const int lane = threadIdx.x & 63;
    const float4 h = *reinterpret_cast<const float4*>(H + (size_t)node * HID + (lane << 2));
    const float4 qv = *reinterpret_cast<const float4*>(q + (lane << 2));
    float d = h.x * qv.x + h.y * qv.y + h.z * qv.z + h.w * qv.w;
#pragma unroll
    for (int off = 32; off > 0; off >>= 1) d += __shfl_xor(d, off);
    if (lane == 0) out[node] = tanhf(d + (r ? r[0] : 0.f));
}

// ---------- per-graph bitonic top-k ----------
template<int NN_, int KK_, int NT_>
__global__ __launch_bounds__(NT_) void k_topk(const float* __restrict__ scores,
        int* __restrict__ perm, float* __restrict__ vals, int* __restrict__ mapping) {
    __shared__ float s[NN_];
    __shared__ int id[NN_];
    const int g = blockIdx.x, tid = threadIdx.x;
    for (int i = tid; i < NN_; i += NT_) { s[i] = scores[g * NN_ + i]; id[i] = i; }
    __syncthreads();
    for (int k = 2; k <= NN_; k <<= 1) {
        for (int j = k >> 1; j > 0; j >>= 1) {
            for (int t = tid; t < NN_; t += NT_) {
                const int ixj = t ^ j;
                if (ixj > t) {
                    const bool desc = ((t & k) == 0);
                    const float s1 = s[t], s2 = s[ixj];
                    const int i1 = id[t], i2 = id[ixj];
                    const bool inOrder = (s1 > s2) || (s1 == s2 && i1 < i2);
                    if (inOrder != desc) { s[t] = s2; s[ixj] = s1; id[t] = i2; id[ixj] = i1; }
                }
            }
            __syncthreads();
        }
    }
    for (int i = tid; i < KK_; i += NT_) {
        const int oid = id[i];
        perm[g * KK_ + i] = g * NN_ + oid;
        vals[g * KK_ + i] = s[i];
        if (mapping) mapping[g * NN_ + oid] = g * KK_ + i;
    }
}

// ---------- pool1 apply: gather+BN+scale, write h1p, x1 readout, bn2 stats ----------
__global__ __launch_bounds__(256) void k_pool1(const float* __restrict__ HG,
        const int* __restrict__ perm, const float* __restrict__ vals,
        const float* __restrict__ scale1, const float* __restrict__ shift1,
        float* __restrict__ H1P, float* __restrict__ X1, float* __restrict__ stats2) {
    const int g = blockIdx.x, c = threadIdx.x;
    const float sc = scale1[c], sh = shift1[c];
    float mx = -FLT_MAX, sm = 0.f, sq = 0.f;
    for (int i = 0; i < K1; ++i) {
        const int idx = g * K1 + i;
        const int srow = perm[idx];
        const float val = vals[idx];
        const float hv = HG[(size_t)srow * HID + c];
        const float xn = (hv * sc + sh) * val;
        H1P[(size_t)idx * HID + c] = xn;
        mx = fmaxf(mx, xn);
        sm += xn;
        sq += xn * xn;
    }
    X1[g * 512 + c] = mx;
    X1[g * 512 + 256 + c] = sm * (1.f / K1);
    unsafeAtomicAdd(&stats2[c], sm);
    unsafeAtomicAdd(&stats2[HID + c], sq);
}

// ---------- h2in = gelu(bn2(h1p)) into A2 right half ----------
__global__ __launch_bounds__(256) void k_h2in(const float* __restrict__ H1P,
        const float* __restrict__ scale2, const float* __restrict__ shift2,
        float* __restrict__ A2) {
    const int total = NN1 * (HID / 4);
    for (int i = blockIdx.x * 256 + threadIdx.x; i < total; i += gridDim.x * 256) {
        const int r = i >> 6, c4 = i & 63;
        const float4 v = reinterpret_cast<const float4*>(H1P)[i];
        const float4 sc = reinterpret_cast<const float4*>(scale2)[c4];
        const float4 sh = reinterpret_cast<const float4*>(shift2)[c4];
        float4 o;
        o.x = gelu_exact(v.x * sc.x + sh.x);
        o.y = gelu_exact(v.y * sc.y + sh.y);
        o.z = gelu_exact(v.z * sc.z + sh.z);
        o.w = gelu_exact(v.w * sc.w + sh.w);
        reinterpret_cast<float4*>(A2)[(size_t)r * 128 + 64 + c4] = o;
    }
}

// ---------- edge remap through mapping ----------
__global__ __launch_bounds__(256) void k_remap(const int* __restrict__ src,
        const int* __restrict__ dst, const int* __restrict__ map,
        int* __restrict__ ns, int* __restrict__ nd) {
    const int e = blockIdx.x * 256 + threadIdx.x;
    const int a = map[src[e]];
    const int b = map[dst[e]];
    const bool ok = (a >= 0) && (b >= 0);
    ns[e] = ok ? a : -1;
    nd[e] = ok ? b : -1;
}

// ---------- x2 readout ----------
__global__ __launch_bounds__(256) void k_x2(const float* __restrict__ H2,
        const int* __restrict__ perm, const float* __restrict__ vals,
        float* __restrict__ X2) {
    const int g = blockIdx.x, c = threadIdx.x;
    float mx = -FLT_MAX, sm = 0.f;
    for (int i = 0; i < K2; ++i) {
        const int idx = g * K2 + i;
        const int srow = perm[idx];
        const float v = H2[(size_t)srow * HID + c] * vals[idx];
        mx = fmaxf(mx, v);
        sm += v;
    }
    X2[g * 512 + c] = mx;
    X2[g * 512 + 256 + c] = sm * (1.f / K2);
}

// ---------- final linear: out = (x1+x2) @ Wl + bl ----------
__global__ __launch_bounds__(256) void k_final(const float* __restrict__ X1,
        const float* __restrict__ X2, const float* __restrict__ Wl,
        const float* __restrict__ bl, float* __restrict__ out) {
    const int g = blockIdx.x, c = threadIdx.x;
    float acc = bl[c];
    for (int k = 0; k < 512; ++k) {
        const float xv = X1[g * 512 + k] + X2[g * 512 + k];
        acc = fmaf(xv, Wl[k * HID + c], acc);
    }
    out[g * HID + c] = acc;
}

extern "C" void kernel_launch(void* const* d_in, const int* in_sizes, int n_in,
                              void* d_out, int out_size, void* d_ws, size_t ws_size,
                              hipStream_t stream) {
    (void)in_sizes; (void)n_in; (void)out_size; (void)ws_size;
    const float* x       = (const float*)d_in[0];
    const int*   src     = (const int*)  d_in[1];
    const int*   dst     = (const int*)  d_in[2];
    const float* W_rel1  = (const float*)d_in[3];
    const float* b_rel1  = (const float*)d_in[4];
    const float* W_root1 = (const float*)d_in[5];
    const float* g1      = (const float*)d_in[6];
    const float* bt1     = (const float*)d_in[7];
    const float* p1      = (const float*)d_in[8];
    const float* g2      = (const float*)d_in[9];
    const float* bt2     = (const float*)d_in[10];
    const float* W_rel2  = (const float*)d_in[11];
    const float* b_rel2  = (const float*)d_in[12];
    const float* W_root2 = (const float*)d_in[13];
    const float* p2      = (const float*)d_in[14];
    const float* Wl      = (const float*)d_in[15];
    const float* bl      = (const float*)d_in[16];
    float* out = (float*)d_out;

    char* w = (char*)d_ws;
    size_t off = 0;
    auto alloc = [&](size_t bytes) -> void* {
        void* p = w + off;
        off += (bytes + 255) & ~(size_t)255;
        return p;
    };
    float* A1     = (float*)alloc((size_t)NN0 * 256 * 4);   // [agg1 | x], later h2
    float* HG     = (float*)alloc((size_t)NN0 * 256 * 4);   // gelu(conv1), later A2
    float* H1P    = (float*)alloc((size_t)NN1 * 256 * 4);
    int*   NS     = (int*)  alloc((size_t)NE * 4);
    int*   ND     = (int*)  alloc((size_t)NE * 4);
    float* SCORES = (float*)alloc((size_t)NN0 * 4);         // reused for pool2
    int*   PERM1  = (int*)  alloc((size_t)NN1 * 4);
    float* VALS1  = (float*)alloc((size_t)NN1 * 4);
    int*   MAP1   = (int*)  alloc((size_t)NN0 * 4);
    int*   PERM2  = (int*)  alloc((size_t)NN2 * 4);
    float* VALS2  = (float*)alloc((size_t)NN2 * 4);
    float* STATS1 = (float*)alloc(512 * 4);
    float* STATS2 = (float*)alloc(512 * 4);
    float* SCALE1 = (float*)alloc(256 * 4);
    float* SHIFT1 = (float*)alloc(256 * 4);
    float* Q1     = (float*)alloc(256 * 4);
    float* R1     = (float*)alloc(256);
    float* SCALE2 = (float*)alloc(256 * 4);
    float* SHIFT2 = (float*)alloc(256 * 4);
    float* Q2     = (float*)alloc(256 * 4);
    float* W1C    = (float*)alloc((size_t)256 * 256 * 4);
    float* W2C    = (float*)alloc((size_t)512 * 256 * 4);
    float* X1     = (float*)alloc((size_t)GG * 512 * 4);
    float* X2     = (float*)alloc((size_t)GG * 512 * 4);
    float* A2 = HG;   // alias: h_gelu dead before A2 is written
    float* H2 = A1;   // alias: A1 dead before h2 is written

    hipMemsetAsync(STATS1, 0, 512 * sizeof(float), stream);
    hipMemsetAsync(STATS2, 0, 512 * sizeof(float), stream);
    hipMemsetAsync(MAP1, 0xFF, (size_t)NN0 * sizeof(int), stream);

    k_w1cat<<<256, 256, 0, stream>>>(W_rel1, W_root1, W1C);
    k_w2cat<<<512, 256, 0, stream>>>(W_rel2, W_root2, W2C);
    k_q2norm<<<1, 256, 0, stream>>>(p2, Q2);
    k_copy_x<<<2048, 256, 0, stream>>>(x, A1);
    k_agg1<<<512, 512, 0, stream>>>(x, src, dst, A1);
    k_gemm128<1><<<dim3(512, 2), 256, 0, stream>>>(A1, W1C, b_rel1, HG, STATS1, NN0, 256, 256);
    k_finalize1<<<1, 256, 0, stream>>>(STATS1, g1, bt1, p1, SCALE1, SHIFT1, Q1, R1);
    k_score<<<NN0 / 4, 256, 0, stream>>>(HG, Q1, R1, SCORES);
    k_topk<NPG, K1, 512><<<GG, 512, 0, stream>>>(SCORES, PERM1, VALS1, MAP1);
    k_pool1<<<GG, 256, 0, stream>>>(HG, PERM1, VALS1, SCALE1, SHIFT1, H1P, X1, STATS2);
    k_finalize2<<<1, 256, 0, stream>>>(STATS2, g2, bt2, SCALE2, SHIFT2);
    k_h2in<<<2048, 256, 0, stream>>>(H1P, SCALE2, SHIFT2, A2);
    k_remap<<<NE / 256, 256, 0, stream>>>(src, dst, MAP1, NS, ND);
    k_agg2<<<512, 512, 0, stream>>>(A2, NS, ND, A2);
    k_gemm128<0><<<dim3(256, 2), 256, 0, stream>>>(A2, W2C, b_rel2, H2, nullptr, NN1, 512, 256);
    k_score<<<NN1 / 4, 256, 0, stream>>>(H2, Q2, nullptr, SCORES);
    k_topk<K1, K2, 256><<<GG, 256, 0, stream>>>(SCORES, PERM2, VALS2, nullptr);
    k_x2<<<GG, 256, 0, stream>>>(H2, PERM2, VALS2, X2);
    k_final<<<GG, 256, 0, stream>>>(X1, X2, Wl, bl, out);
}

// Round 3
// 538.341 us; speedup vs baseline: 1.9825x; 1.9825x over previous
//
#include <hip/hip_runtime.h>
#include <hip/hip_bf16.h>
#include <float.h>

#define GG    64
#define NPG   1024
#define EPG   8192      // edges per graph
#define NE    524288
#define FIN   128
#define HID   256
#define K1    512
#define K2    256
#define NN0   65536     // GG*NPG
#define NN1   32768     // GG*K1
#define NN2   16384     // GG*K2
#define EPSBN 1e-5f

__device__ __forceinline__ float gelu_exact(float v) {
    return 0.5f * v * (1.0f + erff(v * 0.7071067811865476f));
}

// ---------- small prep kernels ----------
__global__ __launch_bounds__(256) void k_w1cat(const float* __restrict__ Wrel,
        const float* __restrict__ Wroot, float* __restrict__ Wc) {
    const int i = blockIdx.x * 256 + threadIdx.x;       // 65536 = 256x256
    const int k = i >> 8, n = i & 255;
    Wc[i] = (k < FIN) ? Wrel[k * HID + n] : Wroot[(k - FIN) * HID + n];
}

__global__ __launch_bounds__(256) void k_w2cat(const float* __restrict__ Wrel,
        const float* __restrict__ Wroot, float* __restrict__ Wc) {
    const int i = blockIdx.x * 256 + threadIdx.x;       // 131072 = 512x256
    const int k = i >> 8, n = i & 255;
    Wc[i] = (k < HID) ? Wrel[k * HID + n] : Wroot[(k - HID) * HID + n];
}

__global__ __launch_bounds__(256) void k_q2norm(const float* __restrict__ p2,
        float* __restrict__ q2) {
    __shared__ float red[256];
    const int c = threadIdx.x;
    const float pv = p2[c];
    red[c] = pv * pv;
    __syncthreads();
    for (int s = 128; s > 0; s >>= 1) {
        if (c < s) red[c] += red[c + s];
        __syncthreads();
    }
    q2[c] = pv * rsqrtf(red[0]);
}

__global__ __launch_bounds__(256) void k_copy_x(const float* __restrict__ x,
        float* __restrict__ A1) {
    const int total = NN0 * (FIN / 4);                  // float4 count
    for (int i = blockIdx.x * 256 + threadIdx.x; i < total; i += gridDim.x * 256) {
        const int r = i >> 5, c4 = i & 31;
        reinterpret_cast<float4*>(A1)[(size_t)r * 64 + 32 + c4] =
            reinterpret_cast<const float4*>(x)[i];
    }
}

// ---------- CSR build: bucket edges by dst, one block per graph ----------
__global__ __launch_bounds__(512) void k_csr(const int* __restrict__ src,
        const int* __restrict__ dst, int* __restrict__ rowp,
        int* __restrict__ ssrc) {
    __shared__ int cnt[NPG];
    __shared__ int sa[NPG];
    __shared__ int sb[NPG];
    const int g = blockIdx.x, tid = threadIdx.x;
    const int eb = g * EPG;
    for (int i = tid; i < NPG; i += 512) cnt[i] = 0;
    __syncthreads();
    for (int e = tid; e < EPG; e += 512)
        atomicAdd(&cnt[dst[eb + e] & (NPG - 1)], 1);
    __syncthreads();
    for (int i = tid; i < NPG; i += 512) sa[i] = cnt[i];
    __syncthreads();
    int* cur = sa; int* nxt = sb;
    for (int d = 1; d < NPG; d <<= 1) {                 // inclusive scan
        for (int i = tid; i < NPG; i += 512)
            nxt[i] = cur[i] + ((i >= d) ? cur[i - d] : 0);
        __syncthreads();
        int* t = cur; cur = nxt; nxt = t;
    }
    for (int i = tid; i < NPG; i += 512) {
        const int st = cur[i] - cnt[i];                 // exclusive start
        rowp[g * (NPG + 1) + i] = st;
        cnt[i] = st;                                    // reuse as cursor
    }
    if (tid == 0) rowp[g * (NPG + 1) + NPG] = EPG;
    __syncthreads();
    for (int e = tid; e < EPG; e += 512) {
        const int d = dst[eb + e] & (NPG - 1);
        const int p = atomicAdd(&cnt[d], 1);
        ssrc[eb + p] = src[eb + e] & (NPG - 1);
    }
}

// ---------- agg1: CSR gather-sum, register accumulate, no atomics ----------
// grid 8192 = 128 node-groups x 64 graphs; b = ng*64 + g pins graph g to XCD g%8.
// 256 threads = 8 nodes x 32 col-float4s (128 cols).
__global__ __launch_bounds__(256) void k_agg1(const float* __restrict__ x,
        const int* __restrict__ rowp, const int* __restrict__ ssrc,
        float* __restrict__ A1) {
    const int b = blockIdx.x;
    const int g = b & 63;
    const int ng = b >> 6;                              // 0..127
    const int tid = threadIdx.x;
    const int ln = tid & 31;                            // col float4 0..31
    const int node = (ng << 3) + (tid >> 5);            // 0..1023
    const int s0 = rowp[g * (NPG + 1) + node];
    const int s1 = rowp[g * (NPG + 1) + node + 1];
    const float4* x4 = reinterpret_cast<const float4*>(x);
    const size_t gb = (size_t)(g << 10) * 32;           // 32 float4 per x row
    const int* sp = ssrc + (size_t)g * EPG;
    float4 acc = make_float4(0.f, 0.f, 0.f, 0.f);
    for (int j = s0; j < s1; ++j) {
        const float4 v = x4[gb + (size_t)sp[j] * 32 + ln];
        acc.x += v.x; acc.y += v.y; acc.z += v.z; acc.w += v.w;
    }
    reinterpret_cast<float4*>(A1)[((size_t)((g << 10) + node)) * 64 + ln] = acc;
}

// ---------- agg2: reuse layer-1 CSR buckets of kept dst nodes ----------
// grid 8192 = 128 node-groups x 64 graphs; 256 threads = 4 nodes x 64 col-float4s.
__global__ __launch_bounds__(256) void k_agg2(const float* __restrict__ A2r,
        const int* __restrict__ rowp, const int* __restrict__ ssrc,
        const int* __restrict__ perm1, const int* __restrict__ map1,
        float* __restrict__ A2w) {
    const int b = blockIdx.x;
    const int g = b & 63;
    const int ng = b >> 6;                              // 0..127
    const int tid = threadIdx.x;
    const int ln = tid & 63;                            // col float4 0..63
    const int ni = (ng << 2) + (tid >> 6);              // new node 0..511
    const int on = perm1[(g << 9) + ni] & (NPG - 1);    // old node id
    const int s0 = rowp[g * (NPG + 1) + on];
    const int s1 = rowp[g * (NPG + 1) + on + 1];
    const float4* h4 = reinterpret_cast<const float4*>(A2r);
    const int* sp = ssrc + (size_t)g * EPG;
    const int* mp = map1 + ((size_t)g << 10);
    float4 acc = make_float4(0.f, 0.f, 0.f, 0.f);
    for (int j = s0; j < s1; ++j) {
        const int ms = mp[sp[j]];                       // global new id or -1
        if (ms < 0) continue;                           // lane-uniform branch
        const float4 v = h4[(size_t)ms * 128 + 64 + ln];
        acc.x += v.x; acc.y += v.y; acc.z += v.z; acc.w += v.w;
    }
    reinterpret_cast<float4*>(A2w)[((size_t)((g << 9) + ni)) * 128 + ln] = acc;
}

// ---------- fp32 SGEMM, 128x128 tile, optional gelu+BN-stats epilogue ----------
template<int EPI>   // 0: +bias; 1: +bias, gelu, column sum/sumsq stats
__global__ __launch_bounds__(256) void k_gemm128(
        const float* __restrict__ A, const float* __restrict__ B,
        const float* __restrict__ bias, float* __restrict__ C,
        float* __restrict__ stats, int M, int K, int N) {
    __shared__ float As[16][128];
    __shared__ float Bs[16][128];
    __shared__ float csum[128];
    __shared__ float csq[128];
    const int tid = threadIdx.x;
    const int tx = tid & 15, ty = tid >> 4;
    const int m0 = blockIdx.x * 128, n0 = blockIdx.y * 128;

    float acc[8][8];
#pragma unroll
    for (int i = 0; i < 8; ++i)
#pragma unroll
        for (int j = 0; j < 8; ++j) acc[i][j] = 0.f;

    const int ar = tid >> 2, akc = (tid & 3) << 2;
    const int bkr = tid >> 4, bnc = (tid & 15) << 3;

    for (int k0 = 0; k0 < K; k0 += 16) {
        const float4 a0 = *reinterpret_cast<const float4*>(A + (size_t)(m0 + ar) * K + k0 + akc);
        const float4 a1 = *reinterpret_cast<const float4*>(A + (size_t)(m0 + ar + 64) * K + k0 + akc);
        const float4 b0 = *reinterpret_cast<const float4*>(B + (size_t)(k0 + bkr) * N + n0 + bnc);
        const float4 b1 = *reinterpret_cast<const float4*>(B + (size_t)(k0 + bkr) * N + n0 + bnc + 4);
        __syncthreads();
        As[akc + 0][ar] = a0.x; As[akc + 1][ar] = a0.y; As[akc + 2][ar] = a0.z; As[akc + 3][ar] = a0.w;
        As[akc + 0][ar + 64] = a1.x; As[akc + 1][ar + 64] = a1.y; As[akc + 2][ar + 64] = a1.z; As[akc + 3][ar + 64] = a1.w;
        *reinterpret_cast<float4*>(&Bs[bkr][bnc]) = b0;
        *reinterpret_cast<float4*>(&Bs[bkr][bnc + 4]) = b1;
        __syncthreads();
#pragma unroll
        for (int k = 0; k < 16; ++k) {
            const float4 av0 = *reinterpret_cast<const float4*>(&As[k][ty << 2]);
            const float4 av1 = *reinterpret_cast<const float4*>(&As[k][64 + (ty << 2)]);
            const float4 bv0 = *reinterpret_cast<const float4*>(&Bs[k][tx << 2]);
            const float4 bv1 = *reinterpret_cast<const float4*>(&Bs[k][64 + (tx << 2)]);
            const float a[8] = {av0.x, av0.y, av0.z, av0.w, av1.x, av1.y, av1.z, av1.w};
            const float b[8] = {bv0.x, bv0.y, bv0.z, bv0.w, bv1.x, bv1.y, bv1.z, bv1.w};
#pragma unroll
            for (int i = 0; i < 8; ++i)
#pragma unroll
                for (int j = 0; j < 8; ++j) acc[i][j] = fmaf(a[i], b[j], acc[i][j]);
        }
    }

    if (EPI == 1) {
        if (tid < 128) { csum[tid] = 0.f; csq[tid] = 0.f; }
        __syncthreads();
    }

    const float4 bia0 = *reinterpret_cast<const float4*>(bias + n0 + (tx << 2));
    const float4 bia1 = *reinterpret_cast<const float4*>(bias + n0 + 64 + (tx << 2));
    const float bcol[8] = {bia0.x, bia0.y, bia0.z, bia0.w, bia1.x, bia1.y, bia1.z, bia1.w};
    float sArr[8] = {0, 0, 0, 0, 0, 0, 0, 0};
    float qArr[8] = {0, 0, 0, 0, 0, 0, 0, 0};

#pragma unroll
    for (int i = 0; i < 8; ++i) {
        const int row = m0 + ((i < 4) ? ((ty << 2) + i) : (64 + (ty << 2) + i - 4));
        float v[8];
#pragma unroll
        for (int j = 0; j < 8; ++j) {
            float t = acc[i][j] + bcol[j];
            if (EPI == 1) {
                t = gelu_exact(t);
                sArr[j] += t;
                qArr[j] += t * t;
            }
            v[j] = t;
        }
        *reinterpret_cast<float4*>(C + (size_t)row * N + n0 + (tx << 2)) =
            make_float4(v[0], v[1], v[2], v[3]);
        *reinterpret_cast<float4*>(C + (size_t)row * N + n0 + 64 + (tx << 2)) =
            make_float4(v[4], v[5], v[6], v[7]);
    }
    if (EPI == 1) {
#pragma unroll
        for (int j = 0; j < 8; ++j) {
            const int cl = (j < 4) ? ((tx << 2) + j) : (64 + (tx << 2) + j - 4);
            unsafeAtomicAdd(&csum[cl], sArr[j]);
            unsafeAtomicAdd(&csq[cl], qArr[j]);
        }
        __syncthreads();
        if (tid < 128) {
            unsafeAtomicAdd(&stats[n0 + tid], csum[tid]);
            unsafeAtomicAdd(&stats[HID + n0 + tid], csq[tid]);
        }
    }
}

// ---------- BN finalize / score fold ----------
__global__ __launch_bounds__(256) void k_finalize1(const float* __restrict__ stats,
        const float* __restrict__ g1, const float* __restrict__ bt1,
        const float* __restrict__ p1, float* __restrict__ scale,
        float* __restrict__ shift, float* __restrict__ q, float* __restrict__ r) {
    __shared__ float red[256];
    const int c = threadIdx.x;
    const float m = stats[c] * (1.f / NN0);
    const float v = stats[HID + c] * (1.f / NN0) - m * m;
    const float sc = g1[c] * rsqrtf(v + EPSBN);
    const float sh = bt1[c] - m * sc;
    scale[c] = sc;
    shift[c] = sh;
    const float pv = p1[c];
    red[c] = pv * pv;
    __syncthreads();
    for (int s = 128; s > 0; s >>= 1) {
        if (c < s) red[c] += red[c + s];
        __syncthreads();
    }
    const float inv = rsqrtf(red[0]);
    q[c] = sc * pv * inv;
    __syncthreads();
    red[c] = sh * pv * inv;
    __syncthreads();
    for (int s = 128; s > 0; s >>= 1) {
        if (c < s) red[c] += red[c + s];
        __syncthreads();
    }
    if (c == 0) r[0] = red[0];
}

__global__ __launch_bounds__(256) void k_finalize2(const float* __restrict__ stats,
        const float* __restrict__ g2, const float* __restrict__ bt2,
        float* __restrict__ scale, float* __restrict__ shift) {
    const int c = threadIdx.x;
    const float m = stats[c] * (1.f / NN1);
    const float v = stats[HID + c] * (1.f / NN1) - m * m;
    const float sc = g2[c] * rsqrtf(v + EPSBN);
    scale[c] = sc;
    shift[c] = bt2[c] - m * sc;
}

// ---------- scores: tanh(h . q + r), one wave per node ----------
__global__ __launch_bounds__(256) void k_score(const float* __restrict__ H,
        const float* __restrict__ q, const float* __restrict__ r,
        float* __restrict__ out) {
    const int node = blockIdx.x * 4 + (threadIdx.x >> 6);
    const int lane = threadIdx.x & 63;
    const float4 h = *reinterpret_cast<const float4*>(H + (size_t)node * HID + (lane << 2));
    const float4 qv = *reinterpret_cast<const float4*>(q + (lane << 2));
    float d = h.x * qv.x + h.y * qv.y + h.z * qv.z + h.w * qv.w;
#pragma unroll
    for (int off = 32; off > 0; off >>= 1) d += __shfl_xor(d, off);
    if (lane == 0) out[node] = tanhf(d + (r ? r[0] : 0.f));
}

// ---------- per-graph bitonic top-k ----------
template<int NN_, int KK_, int NT_>
__global__ __launch_bounds__(NT_) void k_topk(const float* __restrict__ scores,
        int* __restrict__ perm, float* __restrict__ vals, int* __restrict__ mapping) {
    __shared__ float s[NN_];
    __shared__ int id[NN_];
    const int g = blockIdx.x, tid = threadIdx.x;
    for (int i = tid; i < NN_; i += NT_) { s[i] = scores[g * NN_ + i]; id[i] = i; }
    __syncthreads();
    for (int k = 2; k <= NN_; k <<= 1) {
        for (int j = k >> 1; j > 0; j >>= 1) {
            for (int t = tid; t < NN_; t += NT_) {
                const int ixj = t ^ j;
                if (ixj > t) {
                    const bool desc = ((t & k) == 0);
                    const float s1 = s[t], s2 = s[ixj];
                    const int i1 = id[t], i2 = id[ixj];
                    const bool inOrder = (s1 > s2) || (s1 == s2 && i1 < i2);
                    if (inOrder != desc) { s[t] = s2; s[ixj] = s1; id[t] = i2; id[ixj] = i1; }
                }
            }
            __syncthreads();
        }
    }
    for (int i = tid; i < KK_; i += NT_) {
        const int oid = id[i];
        perm[g * KK_ + i] = g * NN_ + oid;
        vals[g * KK_ + i] = s[i];
        if (mapping) mapping[g * NN_ + oid] = g * KK_ + i;
    }
}

// ---------- pool1 apply: gather+BN+scale, write h1p, x1 readout, bn2 stats ----------
__global__ __launch_bounds__(256) void k_pool1(const float* __restrict__ HG,
        const int* __restrict__ perm, const float* __restrict__ vals,
        const float* __restrict__ scale1, const float* __restrict__ shift1,
        float* __restrict__ H1P, float* __restrict__ X1, float* __restrict__ stats2) {
    const int g = blockIdx.x, c = threadIdx.x;
    const float sc = scale1[c], sh = shift1[c];
    float mx = -FLT_MAX, sm = 0.f, sq = 0.f;
    for (int i = 0; i < K1; ++i) {
        const int idx = g * K1 + i;
        const int srow = perm[idx];
        const float val = vals[idx];
        const float hv = HG[(size_t)srow * HID + c];
        const float xn = (hv * sc + sh) * val;
        H1P[(size_t)idx * HID + c] = xn;
        mx = fmaxf(mx, xn);
        sm += xn;
        sq += xn * xn;
    }
    X1[g * 512 + c] = mx;
    X1[g * 512 + 256 + c] = sm * (1.f / K1);
    unsafeAtomicAdd(&stats2[c], sm);
    unsafeAtomicAdd(&stats2[HID + c], sq);
}

// ---------- h2in = gelu(bn2(h1p)) into A2 right half ----------
__global__ __launch_bounds__(256) void k_h2in(const float* __restrict__ H1P,
        const float* __restrict__ scale2, const float* __restrict__ shift2,
        float* __restrict__ A2) {
    const int total = NN1 * (HID / 4);
    for (int i = blockIdx.x * 256 + threadIdx.x; i < total; i += gridDim.x * 256) {
        const int r = i >> 6, c4 = i & 63;
        const float4 v = reinterpret_cast<const float4*>(H1P)[i];
        const float4 sc = reinterpret_cast<const float4*>(scale2)[c4];
        const float4 sh = reinterpret_cast<const float4*>(shift2)[c4];
        float4 o;
        o.x = gelu_exact(v.x * sc.x + sh.x);
        o.y = gelu_exact(v.y * sc.y + sh.y);
        o.z = gelu_exact(v.z * sc.z + sh.z);
        o.w = gelu_exact(v.w * sc.w + sh.w);
        reinterpret_cast<float4*>(A2)[(size_t)r * 128 + 64 + c4] = o;
    }
}

// ---------- x2 readout ----------
__global__ __launch_bounds__(256) void k_x2(const float* __restrict__ H2,
        const int* __restrict__ perm, const float* __restrict__ vals,
        float* __restrict__ X2) {
    const int g = blockIdx.x, c = threadIdx.x;
    float mx = -FLT_MAX, sm = 0.f;
    for (int i = 0; i < K2; ++i) {
        const int idx = g * K2 + i;
        const int srow = perm[idx];
        const float v = H2[(size_t)srow * HID + c] * vals[idx];
        mx = fmaxf(mx, v);
        sm += v;
    }
    X2[g * 512 + c] = mx;
    X2[g * 512 + 256 + c] = sm * (1.f / K2);
}

// ---------- final linear: out = (x1+x2) @ Wl + bl ----------
__global__ __launch_bounds__(256) void k_final(const float* __restrict__ X1,
        const float* __restrict__ X2, const float* __restrict__ Wl,
        const float* __restrict__ bl, float* __restrict__ out) {
    const int g = blockIdx.x, c = threadIdx.x;
    float acc = bl[c];
    for (int k = 0; k < 512; ++k) {
        const float xv = X1[g * 512 + k] + X2[g * 512 + k];
        acc = fmaf(xv, Wl[k * HID + c], acc);
    }
    out[g * HID + c] = acc;
}

extern "C" void kernel_launch(void* const* d_in, const int* in_sizes, int n_in,
                              void* d_out, int out_size, void* d_ws, size_t ws_size,
                              hipStream_t stream) {
    (void)in_sizes; (void)n_in; (void)out_size; (void)ws_size;
    const float* x       = (const float*)d_in[0];
    const int*   src     = (const int*)  d_in[1];
    const int*   dst     = (const int*)  d_in[2];
    const float* W_rel1  = (const float*)d_in[3];
    const float* b_rel1  = (const float*)d_in[4];
    const float* W_root1 = (const float*)d_in[5];
    const float* g1      = (const float*)d_in[6];
    const float* bt1     = (const float*)d_in[7];
    const float* p1      = (const float*)d_in[8];
    const float* g2      = (const float*)d_in[9];
    const float* bt2     = (const float*)d_in[10];
    const float* W_rel2  = (const float*)d_in[11];
    const float* b_rel2  = (const float*)d_in[12];
    const float* W_root2 = (const float*)d_in[13];
    const float* p2      = (const float*)d_in[14];
    const float* Wl      = (const float*)d_in[15];
    const float* bl      = (const float*)d_in[16];
    float* out = (float*)d_out;

    char* w = (char*)d_ws;
    size_t off = 0;
    auto alloc = [&](size_t bytes) -> void* {
        void* p = w + off;
        off += (bytes + 255) & ~(size_t)255;
        return p;
    };
    float* A1     = (float*)alloc((size_t)NN0 * 256 * 4);   // [agg1 | x], later h2
    float* HG     = (float*)alloc((size_t)NN0 * 256 * 4);   // gelu(conv1), later A2
    float* H1P    = (float*)alloc((size_t)NN1 * 256 * 4);
    int*   ROWP   = (int*)  alloc((size_t)GG * (NPG + 1) * 4);
    int*   SSRC   = (int*)  alloc((size_t)NE * 4);
    float* SCORES = (float*)alloc((size_t)NN0 * 4);         // reused for pool2
    int*   PERM1  = (int*)  alloc((size_t)NN1 * 4);
    float* VALS1  = (float*)alloc((size_t)NN1 * 4);
    int*   MAP1   = (int*)  alloc((size_t)NN0 * 4);
    int*   PERM2  = (int*)  alloc((size_t)NN2 * 4);
    float* VALS2  = (float*)alloc((size_t)NN2 * 4);
    float* STATS1 = (float*)alloc(512 * 4);
    float* STATS2 = (float*)alloc(512 * 4);
    float* SCALE1 = (float*)alloc(256 * 4);
    float* SHIFT1 = (float*)alloc(256 * 4);
    float* Q1     = (float*)alloc(256 * 4);
    float* R1     = (float*)alloc(256);
    float* SCALE2 = (float*)alloc(256 * 4);
    float* SHIFT2 = (float*)alloc(256 * 4);
    float* Q2     = (float*)alloc(256 * 4);
    float* W1C    = (float*)alloc((size_t)256 * 256 * 4);
    float* W2C    = (float*)alloc((size_t)512 * 256 * 4);
    float* X1     = (float*)alloc((size_t)GG * 512 * 4);
    float* X2     = (float*)alloc((size_t)GG * 512 * 4);
    float* A2 = HG;   // alias: h_gelu dead before A2 is written
    float* H2 = A1;   // alias: A1 dead before h2 is written

    hipMemsetAsync(STATS1, 0, 512 * sizeof(float), stream);
    hipMemsetAsync(STATS2, 0, 512 * sizeof(float), stream);
    hipMemsetAsync(MAP1, 0xFF, (size_t)NN0 * sizeof(int), stream);

    k_csr<<<GG, 512, 0, stream>>>(src, dst, ROWP, SSRC);
    k_w1cat<<<256, 256, 0, stream>>>(W_rel1, W_root1, W1C);
    k_w2cat<<<512, 256, 0, stream>>>(W_rel2, W_root2, W2C);
    k_q2norm<<<1, 256, 0, stream>>>(p2, Q2);
    k_copy_x<<<2048, 256, 0, stream>>>(x, A1);
    k_agg1<<<8192, 256, 0, stream>>>(x, ROWP, SSRC, A1);
    k_gemm128<1><<<dim3(512, 2), 256, 0, stream>>>(A1, W1C, b_rel1, HG, STATS1, NN0, 256, 256);
    k_finalize1<<<1, 256, 0, stream>>>(STATS1, g1, bt1, p1, SCALE1, SHIFT1, Q1, R1);
    k_score<<<NN0 / 4, 256, 0, stream>>>(HG, Q1, R1, SCORES);
    k_topk<NPG, K1, 512><<<GG, 512, 0, stream>>>(SCORES, PERM1, VALS1, MAP1);
    k_pool1<<<GG, 256, 0, stream>>>(HG, PERM1, VALS1, SCALE1, SHIFT1, H1P, X1, STATS2);
    k_finalize2<<<1, 256, 0, stream>>>(STATS2, g2, bt2, SCALE2, SHIFT2);
    k_h2in<<<2048, 256, 0, stream>>>(H1P, SCALE2, SHIFT2, A2);
    k_agg2<<<8192, 256, 0, stream>>>(A2, ROWP, SSRC, PERM1, MAP1, A2);
    k_gemm128<0><<<dim3(256, 2), 256, 0, stream>>>(A2, W2C, b_rel2, H2, nullptr, NN1, 512, 256);
    k_score<<<NN1 / 4, 256, 0, stream>>>(H2, Q2, nullptr, SCORES);
    k_topk<K1, K2, 256><<<GG, 256, 0, stream>>>(SCORES, PERM2, VALS2, nullptr);
    k_x2<<<GG, 256, 0, stream>>>(H2, PERM2, VALS2, X2);
    k_final<<<GG, 256, 0, stream>>>(X1, X2, Wl, bl, out);
}

// Round 5
// 408.962 us; speedup vs baseline: 2.6097x; 1.3164x over previous
//
#include <hip/hip_runtime.h>
#include <hip/hip_bf16.h>
#include <float.h>

#define GG    64
#define NPG   1024
#define EPG   8192      // edges per graph
#define NE    524288
#define FIN   128
#define HID   256
#define K1    512
#define K2    256
#define NN0   65536     // GG*NPG
#define NN1   32768     // GG*K1
#define NN2   16384     // GG*K2
#define EPSBN 1e-5f

typedef short bf16x8 __attribute__((ext_vector_type(8)));
typedef float f32x4 __attribute__((ext_vector_type(4)));

__device__ __forceinline__ float gelu_exact(float v) {
    return 0.5f * v * (1.0f + erff(v * 0.7071067811865476f));
}

__device__ __forceinline__ unsigned short f2bf(float f) {
    union { float f; unsigned int u; } v; v.f = f;
    const unsigned int u = v.u;
    return (unsigned short)((u + 0x7FFFu + ((u >> 16) & 1u)) >> 16);   // RNE
}

__device__ __forceinline__ float bf2f(unsigned short h) {
    union { unsigned int u; float f; } v; v.u = ((unsigned int)h) << 16;
    return v.f;
}

// split fp32 -> hi/lo bf16 (hi + lo carries ~16 mantissa bits)
__device__ __forceinline__ void split_bf(float v, unsigned short& hi, unsigned short& lo) {
    hi = f2bf(v);
    lo = f2bf(v - bf2f(hi));
}

// ---------- weight transpose+concat to split-bf16 [N][K] ----------
__global__ __launch_bounds__(256) void k_w1t(const float* __restrict__ Wrel,
        const float* __restrict__ Wroot, unsigned short* __restrict__ WTh,
        unsigned short* __restrict__ WTl) {
    const int i = blockIdx.x * 256 + threadIdx.x;       // 65536 = 256n x 256k
    const int n = i >> 8, k = i & 255;
    const float v = (k < FIN) ? Wrel[k * HID + n] : Wroot[(k - FIN) * HID + n];
    unsigned short hi, lo; split_bf(v, hi, lo);
    WTh[i] = hi; WTl[i] = lo;
}

__global__ __launch_bounds__(256) void k_w2t(const float* __restrict__ Wrel,
        const float* __restrict__ Wroot, unsigned short* __restrict__ WTh,
        unsigned short* __restrict__ WTl) {
    const int i = blockIdx.x * 256 + threadIdx.x;       // 131072 = 256n x 512k
    const int n = i >> 9, k = i & 511;
    const float v = (k < HID) ? Wrel[k * HID + n] : Wroot[(k - HID) * HID + n];
    unsigned short hi, lo; split_bf(v, hi, lo);
    WTh[i] = hi; WTl[i] = lo;
}

__global__ __launch_bounds__(256) void k_q2norm(const float* __restrict__ p2,
        float* __restrict__ q2) {
    __shared__ float red[256];
    const int c = threadIdx.x;
    const float pv = p2[c];
    red[c] = pv * pv;
    __syncthreads();
    for (int s = 128; s > 0; s >>= 1) {
        if (c < s) red[c] += red[c + s];
        __syncthreads();
    }
    q2[c] = pv * rsqrtf(red[0]);
}

__global__ __launch_bounds__(256) void k_copy_x(const float* __restrict__ x,
        unsigned short* __restrict__ A1h, unsigned short* __restrict__ A1l) {
    const int total = NN0 * (FIN / 4);                  // float4 count
    for (int i = blockIdx.x * 256 + threadIdx.x; i < total; i += gridDim.x * 256) {
        const int r = i >> 5, c4 = i & 31;
        const float4 v = reinterpret_cast<const float4*>(x)[i];
        ushort4 h, l;
        split_bf(v.x, h.x, l.x); split_bf(v.y, h.y, l.y);
        split_bf(v.z, h.z, l.z); split_bf(v.w, h.w, l.w);
        const size_t o = (size_t)r * 256 + 128 + (c4 << 2);
        *reinterpret_cast<ushort4*>(&A1h[o]) = h;
        *reinterpret_cast<ushort4*>(&A1l[o]) = l;
    }
}

// ---------- CSR build: bucket edges by dst, one block per graph ----------
__global__ __launch_bounds__(512) void k_csr(const int* __restrict__ src,
        const int* __restrict__ dst, int* __restrict__ rowp,
        int* __restrict__ ssrc) {
    __shared__ int cnt[NPG];
    __shared__ int sa[NPG];
    __shared__ int sb[NPG];
    const int g = blockIdx.x, tid = threadIdx.x;
    const int eb = g * EPG;
    for (int i = tid; i < NPG; i += 512) cnt[i] = 0;
    __syncthreads();
    for (int e = tid; e < EPG; e += 512)
        atomicAdd(&cnt[dst[eb + e] & (NPG - 1)], 1);
    __syncthreads();
    for (int i = tid; i < NPG; i += 512) sa[i] = cnt[i];
    __syncthreads();
    int* cur = sa; int* nxt = sb;
    for (int d = 1; d < NPG; d <<= 1) {                 // inclusive scan
        for (int i = tid; i < NPG; i += 512)
            nxt[i] = cur[i] + ((i >= d) ? cur[i - d] : 0);
        __syncthreads();
        int* t = cur; cur = nxt; nxt = t;
    }
    for (int i = tid; i < NPG; i += 512) {
        const int st = cur[i] - cnt[i];                 // exclusive start
        rowp[g * (NPG + 1) + i] = st;
        cnt[i] = st;                                    // reuse as cursor
    }
    if (tid == 0) rowp[g * (NPG + 1) + NPG] = EPG;
    __syncthreads();
    for (int e = tid; e < EPG; e += 512) {
        const int d = dst[eb + e] & (NPG - 1);
        const int p = atomicAdd(&cnt[d], 1);
        ssrc[eb + p] = src[eb + e] & (NPG - 1);
    }
}

// ---------- agg1: CSR gather-sum, fp32 accumulate, split-bf16 out ----------
__global__ __launch_bounds__(256) void k_agg1(const float* __restrict__ x,
        const int* __restrict__ rowp, const int* __restrict__ ssrc,
        unsigned short* __restrict__ A1h, unsigned short* __restrict__ A1l) {
    const int b = blockIdx.x;
    const int g = b & 63;
    const int ng = b >> 6;                              // 0..127
    const int tid = threadIdx.x;
    const int ln = tid & 31;                            // col float4 0..31
    const int node = (ng << 3) + (tid >> 5);            // 0..1023
    const int s0 = rowp[g * (NPG + 1) + node];
    const int s1 = rowp[g * (NPG + 1) + node + 1];
    const float4* x4 = reinterpret_cast<const float4*>(x);
    const size_t gb = (size_t)(g << 10) * 32;           // 32 float4 per x row
    const int* sp = ssrc + (size_t)g * EPG;
    float4 acc = make_float4(0.f, 0.f, 0.f, 0.f);
    for (int j = s0; j < s1; ++j) {
        const float4 v = x4[gb + (size_t)sp[j] * 32 + ln];
        acc.x += v.x; acc.y += v.y; acc.z += v.z; acc.w += v.w;
    }
    ushort4 h, l;
    split_bf(acc.x, h.x, l.x); split_bf(acc.y, h.y, l.y);
    split_bf(acc.z, h.z, l.z); split_bf(acc.w, h.w, l.w);
    const size_t o = ((size_t)((g << 10) + node)) * 256 + (ln << 2);
    *reinterpret_cast<ushort4*>(&A1h[o]) = h;
    *reinterpret_cast<ushort4*>(&A1l[o]) = l;
}

// ---------- agg2: reuse layer-1 CSR buckets, fp32 in, split-bf16 out ----------
__global__ __launch_bounds__(256) void k_agg2(const float* __restrict__ H2F,
        const int* __restrict__ rowp, const int* __restrict__ ssrc,
        const int* __restrict__ perm1, const int* __restrict__ map1,
        unsigned short* __restrict__ A2h, unsigned short* __restrict__ A2l) {
    const int b = blockIdx.x;
    const int g = b & 63;
    const int ng = b >> 6;                              // 0..127
    const int tid = threadIdx.x;
    const int ln = tid & 63;                            // col float4 0..63
    const int ni = (ng << 2) + (tid >> 6);              // new node 0..511
    const int on = perm1[(g << 9) + ni] & (NPG - 1);    // old node id
    const int s0 = rowp[g * (NPG + 1) + on];
    const int s1 = rowp[g * (NPG + 1) + on + 1];
    const float4* h4 = reinterpret_cast<const float4*>(H2F);
    const int* sp = ssrc + (size_t)g * EPG;
    const int* mp = map1 + ((size_t)g << 10);
    float4 acc = make_float4(0.f, 0.f, 0.f, 0.f);
    for (int j = s0; j < s1; ++j) {
        const int ms = mp[sp[j]];                       // global new id or -1
        if (ms < 0) continue;                           // lane-uniform branch
        const float4 v = h4[(size_t)ms * 64 + ln];
        acc.x += v.x; acc.y += v.y; acc.z += v.z; acc.w += v.w;
    }
    ushort4 h, l;
    split_bf(acc.x, h.x, l.x); split_bf(acc.y, h.y, l.y);
    split_bf(acc.z, h.z, l.z); split_bf(acc.w, h.w, l.w);
    const size_t o = ((size_t)((g << 9) + ni)) * 512 + (ln << 2);
    *reinterpret_cast<ushort4*>(&A2h[o]) = h;
    *reinterpret_cast<ushort4*>(&A2l[o]) = l;
}

// ---------- split-bf16 MFMA GEMM: C = (Ah+Al) @ (Bh+Bl)^T, 3-term ----------
// C[M][256] = A[M][K] @ BT[256][K]^T. 128x128 tile, 4 waves 2x2,
// each wave 64x64 = 4x4 frags of 16x16x32. acc += Ah*Bh + Ah*Bl + Al*Bh.
template<int K, int EPI>   // EPI 0: +bias; 1: +bias, gelu, col sum/sumsq stats
__global__ __launch_bounds__(256) void k_gemm3(
        const unsigned short* __restrict__ Ah, const unsigned short* __restrict__ Al,
        const unsigned short* __restrict__ Bh, const unsigned short* __restrict__ Bl,
        const float* __restrict__ bias, float* __restrict__ C,
        float* __restrict__ stats, int M) {
    constexpr int LK = 40;                              // 32 + 8 pad (80 B rows)
    __shared__ unsigned short Ash[128 * LK];
    __shared__ unsigned short Asl[128 * LK];
    __shared__ unsigned short Bsh[128 * LK];
    __shared__ unsigned short Bsl[128 * LK];
    __shared__ float csum[128];
    __shared__ float csq[128];
    const int tid = threadIdx.x;
    const int l = tid & 63, w = tid >> 6;
    const int wm = w >> 1, wn = w & 1;
    const int m0 = blockIdx.x * 128, n0 = blockIdx.y * 128;
    const int r16 = l & 15, kg = l >> 4;
    const int sr = tid >> 2, sc = tid & 3;              // staging: row, 16B unit

    f32x4 acc[4][4] = {};

    for (int k0 = 0; k0 < K; k0 += 32) {
        const size_t ao0 = (size_t)(m0 + sr) * K + k0 + (sc << 3);
        const size_t ao1 = (size_t)(m0 + sr + 64) * K + k0 + (sc << 3);
        const size_t bo0 = (size_t)(n0 + sr) * K + k0 + (sc << 3);
        const size_t bo1 = (size_t)(n0 + sr + 64) * K + k0 + (sc << 3);
        const uint4 ah0 = *reinterpret_cast<const uint4*>(Ah + ao0);
        const uint4 ah1 = *reinterpret_cast<const uint4*>(Ah + ao1);
        const uint4 al0 = *reinterpret_cast<const uint4*>(Al + ao0);
        const uint4 al1 = *reinterpret_cast<const uint4*>(Al + ao1);
        const uint4 bh0 = *reinterpret_cast<const uint4*>(Bh + bo0);
        const uint4 bh1 = *reinterpret_cast<const uint4*>(Bh + bo1);
        const uint4 bl0 = *reinterpret_cast<const uint4*>(Bl + bo0);
        const uint4 bl1 = *reinterpret_cast<const uint4*>(Bl + bo1);
        __syncthreads();
        *reinterpret_cast<uint4*>(&Ash[sr * LK + (sc << 3)]) = ah0;
        *reinterpret_cast<uint4*>(&Ash[(sr + 64) * LK + (sc << 3)]) = ah1;
        *reinterpret_cast<uint4*>(&Asl[sr * LK + (sc << 3)]) = al0;
        *reinterpret_cast<uint4*>(&Asl[(sr + 64) * LK + (sc << 3)]) = al1;
        *reinterpret_cast<uint4*>(&Bsh[sr * LK + (sc << 3)]) = bh0;
        *reinterpret_cast<uint4*>(&Bsh[(sr + 64) * LK + (sc << 3)]) = bh1;
        *reinterpret_cast<uint4*>(&Bsl[sr * LK + (sc << 3)]) = bl0;
        *reinterpret_cast<uint4*>(&Bsl[(sr + 64) * LK + (sc << 3)]) = bl1;
        __syncthreads();
        bf16x8 afh[4], afl[4], bfh[4], bfl[4];
#pragma unroll
        for (int mi = 0; mi < 4; ++mi) {
            const int ro = (wm * 64 + mi * 16 + r16) * LK + (kg << 3);
            afh[mi] = *reinterpret_cast<const bf16x8*>(&Ash[ro]);
            afl[mi] = *reinterpret_cast<const bf16x8*>(&Asl[ro]);
        }
#pragma unroll
        for (int ni = 0; ni < 4; ++ni) {
            const int ro = (wn * 64 + ni * 16 + r16) * LK + (kg << 3);
            bfh[ni] = *reinterpret_cast<const bf16x8*>(&Bsh[ro]);
            bfl[ni] = *reinterpret_cast<const bf16x8*>(&Bsl[ro]);
        }
#pragma unroll
        for (int mi = 0; mi < 4; ++mi)
#pragma unroll
            for (int ni = 0; ni < 4; ++ni) {
                acc[mi][ni] = __builtin_amdgcn_mfma_f32_16x16x32_bf16(
                    afh[mi], bfh[ni], acc[mi][ni], 0, 0, 0);
                acc[mi][ni] = __builtin_amdgcn_mfma_f32_16x16x32_bf16(
                    afh[mi], bfl[ni], acc[mi][ni], 0, 0, 0);
                acc[mi][ni] = __builtin_amdgcn_mfma_f32_16x16x32_bf16(
                    afl[mi], bfh[ni], acc[mi][ni], 0, 0, 0);
            }
    }

    if (EPI == 1) {
        if (tid < 128) { csum[tid] = 0.f; csq[tid] = 0.f; }
        __syncthreads();
    }

    float sA[4] = {0, 0, 0, 0};
    float qA[4] = {0, 0, 0, 0};
#pragma unroll
    for (int mi = 0; mi < 4; ++mi)
#pragma unroll
        for (int ni = 0; ni < 4; ++ni) {
            const int col = n0 + wn * 64 + ni * 16 + r16;
            const float bc = bias[col];
#pragma unroll
            for (int r = 0; r < 4; ++r) {
                const int row = m0 + wm * 64 + mi * 16 + (kg << 2) + r;
                float t = acc[mi][ni][r] + bc;
                if (EPI == 1) {
                    t = gelu_exact(t);
                    sA[ni] += t;
                    qA[ni] += t * t;
                }
                C[(size_t)row * 256 + col] = t;
            }
        }
    if (EPI == 1) {
#pragma unroll
        for (int ni = 0; ni < 4; ++ni) {
            const int cl = wn * 64 + ni * 16 + r16;
            unsafeAtomicAdd(&csum[cl], sA[ni]);
            unsafeAtomicAdd(&csq[cl], qA[ni]);
        }
        __syncthreads();
        if (tid < 128) {
            unsafeAtomicAdd(&stats[n0 + tid], csum[tid]);
            unsafeAtomicAdd(&stats[HID + n0 + tid], csq[tid]);
        }
    }
}

// ---------- BN finalize / score fold ----------
__global__ __launch_bounds__(256) void k_finalize1(const float* __restrict__ stats,
        const float* __restrict__ g1, const float* __restrict__ bt1,
        const float* __restrict__ p1, float* __restrict__ scale,
        float* __restrict__ shift, float* __restrict__ q, float* __restrict__ r) {
    __shared__ float red[256];
    const int c = threadIdx.x;
    const float m = stats[c] * (1.f / NN0);
    const float v = stats[HID + c] * (1.f / NN0) - m * m;
    const float sc = g1[c] * rsqrtf(v + EPSBN);
    const float sh = bt1[c] - m * sc;
    scale[c] = sc;
    shift[c] = sh;
    const float pv = p1[c];
    red[c] = pv * pv;
    __syncthreads();
    for (int s = 128; s > 0; s >>= 1) {
        if (c < s) red[c] += red[c + s];
        __syncthreads();
    }
    const float inv = rsqrtf(red[0]);
    q[c] = sc * pv * inv;
    __syncthreads();
    red[c] = sh * pv * inv;
    __syncthreads();
    for (int s = 128; s > 0; s >>= 1) {
        if (c < s) red[c] += red[c + s];
        __syncthreads();
    }
    if (c == 0) r[0] = red[0];
}

__global__ __launch_bounds__(256) void k_finalize2(const float* __restrict__ stats,
        const float* __restrict__ g2, const float* __restrict__ bt2,
        float* __restrict__ scale, float* __restrict__ shift) {
    const int c = threadIdx.x;
    const float m = stats[c] * (1.f / NN1);
    const float v = stats[HID + c] * (1.f / NN1) - m * m;
    const float sc = g2[c] * rsqrtf(v + EPSBN);
    scale[c] = sc;
    shift[c] = bt2[c] - m * sc;
}

// ---------- scores: tanh(h . q + r), one wave per node ----------
__global__ __launch_bounds__(256) void k_score(const float* __restrict__ H,
        const float* __restrict__ q, const float* __restrict__ r,
        float* __restrict__ out) {
    const int node = blockIdx.x * 4 + (threadIdx.x >> 6);
    const int lane = threadIdx.x & 63;
    const float4 h = *reinterpret_cast<const float4*>(H + (size_t)node * HID + (lane << 2));
    const float4 qv = *reinterpret_cast<const float4*>(q + (lane << 2));
    float d = h.x * qv.x + h.y * qv.y + h.z * qv.z + h.w * qv.w;
#pragma unroll
    for (int off = 32; off > 0; off >>= 1) d += __shfl_xor(d, off);
    if (lane == 0) out[node] = tanhf(d + (r ? r[0] : 0.f));
}

// ---------- per-graph bitonic top-k ----------
template<int NN_, int KK_, int NT_>
__global__ __launch_bounds__(NT_) void k_topk(const float* __restrict__ scores,
        int* __restrict__ perm, float* __restrict__ vals, int* __restrict__ mapping) {
    __shared__ float s[NN_];
    __shared__ int id[NN_];
    const int g = blockIdx.x, tid = threadIdx.x;
    for (int i = tid; i < NN_; i += NT_) { s[i] = scores[g * NN_ + i]; id[i] = i; }
    __syncthreads();
    for (int k = 2; k <= NN_; k <<= 1) {
        for (int j = k >> 1; j > 0; j >>= 1) {
            for (int t = tid; t < NN_; t += NT_) {
                const int ixj = t ^ j;
                if (ixj > t) {
                    const bool desc = ((t & k) == 0);
                    const float s1 = s[t], s2 = s[ixj];
                    const int i1 = id[t], i2 = id[ixj];
                    const bool inOrder = (s1 > s2) || (s1 == s2 && i1 < i2);
                    if (inOrder != desc) { s[t] = s2; s[ixj] = s1; id[t] = i2; id[ixj] = i1; }
                }
            }
            __syncthreads();
        }
    }
    for (int i = tid; i < KK_; i += NT_) {
        const int oid = id[i];
        perm[g * KK_ + i] = g * NN_ + oid;
        vals[g * KK_ + i] = s[i];
        if (mapping) mapping[g * NN_ + oid] = g * KK_ + i;
    }
}

// ---------- pool1 apply: gather+BN+scale, write h1p, x1 readout, bn2 stats ----------
__global__ __launch_bounds__(256) void k_pool1(const float* __restrict__ HG,
        const int* __restrict__ perm, const float* __restrict__ vals,
        const float* __restrict__ scale1, const float* __restrict__ shift1,
        float* __restrict__ H1P, float* __restrict__ X1, float* __restrict__ stats2) {
    const int g = blockIdx.x, c = threadIdx.x;
    const float sc = scale1[c], sh = shift1[c];
    float mx = -FLT_MAX, sm = 0.f, sq = 0.f;
    for (int i = 0; i < K1; ++i) {
        const int idx = g * K1 + i;
        const int srow = perm[idx];
        const float val = vals[idx];
        const float hv = HG[(size_t)srow * HID + c];
        const float xn = (hv * sc + sh) * val;
        H1P[(size_t)idx * HID + c] = xn;
        mx = fmaxf(mx, xn);
        sm += xn;
        sq += xn * xn;
    }
    X1[g * 512 + c] = mx;
    X1[g * 512 + 256 + c] = sm * (1.f / K1);
    unsafeAtomicAdd(&stats2[c], sm);
    unsafeAtomicAdd(&stats2[HID + c], sq);
}

// ---------- h2in = gelu(bn2(h1p)): fp32 copy + split-bf16 A2 right half ----------
__global__ __launch_bounds__(256) void k_h2in(const float* __restrict__ H1P,
        const float* __restrict__ scale2, const float* __restrict__ shift2,
        unsigned short* __restrict__ A2h, unsigned short* __restrict__ A2l,
        float* __restrict__ H2F) {
    const int total = NN1 * (HID / 4);
    for (int i = blockIdx.x * 256 + threadIdx.x; i < total; i += gridDim.x * 256) {
        const int r = i >> 6, c4 = i & 63;
        const float4 v = reinterpret_cast<const float4*>(H1P)[i];
        const float4 sc = reinterpret_cast<const float4*>(scale2)[c4];
        const float4 sh = reinterpret_cast<const float4*>(shift2)[c4];
        float4 o;
        o.x = gelu_exact(v.x * sc.x + sh.x);
        o.y = gelu_exact(v.y * sc.y + sh.y);
        o.z = gelu_exact(v.z * sc.z + sh.z);
        o.w = gelu_exact(v.w * sc.w + sh.w);
        reinterpret_cast<float4*>(H2F)[i] = o;
        ushort4 h, l;
        split_bf(o.x, h.x, l.x); split_bf(o.y, h.y, l.y);
        split_bf(o.z, h.z, l.z); split_bf(o.w, h.w, l.w);
        const size_t off = (size_t)r * 512 + 256 + (c4 << 2);
        *reinterpret_cast<ushort4*>(&A2h[off]) = h;
        *reinterpret_cast<ushort4*>(&A2l[off]) = l;
    }
}

// ---------- x2 readout ----------
__global__ __launch_bounds__(256) void k_x2(const float* __restrict__ H2,
        const int* __restrict__ perm, const float* __restrict__ vals,
        float* __restrict__ X2) {
    const int g = blockIdx.x, c = threadIdx.x;
    float mx = -FLT_MAX, sm = 0.f;
    for (int i = 0; i < K2; ++i) {
        const int idx = g * K2 + i;
        const int srow = perm[idx];
        const float v = H2[(size_t)srow * HID + c] * vals[idx];
        mx = fmaxf(mx, v);
        sm += v;
    }
    X2[g * 512 + c] = mx;
    X2[g * 512 + 256 + c] = sm * (1.f / K2);
}

// ---------- final linear: out = (x1+x2) @ Wl + bl ----------
__global__ __launch_bounds__(256) void k_final(const float* __restrict__ X1,
        const float* __restrict__ X2, const float* __restrict__ Wl,
        const float* __restrict__ bl, float* __restrict__ out) {
    const int g = blockIdx.x, c = threadIdx.x;
    float acc = bl[c];
    for (int k = 0; k < 512; ++k) {
        const float xv = X1[g * 512 + k] + X2[g * 512 + k];
        acc = fmaf(xv, Wl[k * HID + c], acc);
    }
    out[g * HID + c] = acc;
}

extern "C" void kernel_launch(void* const* d_in, const int* in_sizes, int n_in,
                              void* d_out, int out_size, void* d_ws, size_t ws_size,
                              hipStream_t stream) {
    (void)in_sizes; (void)n_in; (void)out_size; (void)ws_size;
    const float* x       = (const float*)d_in[0];
    const int*   src     = (const int*)  d_in[1];
    const int*   dst     = (const int*)  d_in[2];
    const float* W_rel1  = (const float*)d_in[3];
    const float* b_rel1  = (const float*)d_in[4];
    const float* W_root1 = (const float*)d_in[5];
    const float* g1      = (const float*)d_in[6];
    const float* bt1     = (const float*)d_in[7];
    const float* p1      = (const float*)d_in[8];
    const float* g2      = (const float*)d_in[9];
    const float* bt2     = (const float*)d_in[10];
    const float* W_rel2  = (const float*)d_in[11];
    const float* b_rel2  = (const float*)d_in[12];
    const float* W_root2 = (const float*)d_in[13];
    const float* p2      = (const float*)d_in[14];
    const float* Wl      = (const float*)d_in[15];
    const float* bl      = (const float*)d_in[16];
    float* out = (float*)d_out;

    char* w = (char*)d_ws;
    size_t off = 0;
    auto alloc = [&](size_t bytes) -> void* {
        void* p = w + off;
        off += (bytes + 255) & ~(size_t)255;
        return p;
    };
    unsigned short* A1h = (unsigned short*)alloc((size_t)NN0 * 256 * 2);  // 32 MB
    unsigned short* A1l = (unsigned short*)alloc((size_t)NN0 * 256 * 2);  // 32 MB
    float* HG     = (float*)alloc((size_t)NN0 * 256 * 4);   // 64 MB: gelu(conv1) fp32
    float* H2F    = (float*)alloc((size_t)NN1 * 256 * 4);   // 32 MB: gelu(bn2) fp32
    int*   ROWP   = (int*)  alloc((size_t)GG * (NPG + 1) * 4);
    int*   SSRC   = (int*)  alloc((size_t)NE * 4);
    float* SCORES = (float*)alloc((size_t)NN0 * 4);         // reused for pool2
    int*   PERM1  = (int*)  alloc((size_t)NN1 * 4);
    float* VALS1  = (float*)alloc((size_t)NN1 * 4);
    int*   MAP1   = (int*)  alloc((size_t)NN0 * 4);
    int*   PERM2  = (int*)  alloc((size_t)NN2 * 4);
    float* VALS2  = (float*)alloc((size_t)NN2 * 4);
    float* STATS1 = (float*)alloc(512 * 4);
    float* STATS2 = (float*)alloc(512 * 4);
    float* SCALE1 = (float*)alloc(256 * 4);
    float* SHIFT1 = (float*)alloc(256 * 4);
    float* Q1     = (float*)alloc(256 * 4);
    float* R1     = (float*)alloc(256);
    float* SCALE2 = (float*)alloc(256 * 4);
    float* SHIFT2 = (float*)alloc(256 * 4);
    float* Q2     = (float*)alloc(256 * 4);
    unsigned short* W1Th = (unsigned short*)alloc((size_t)256 * 256 * 2);
    unsigned short* W1Tl = (unsigned short*)alloc((size_t)256 * 256 * 2);
    unsigned short* W2Th = (unsigned short*)alloc((size_t)256 * 512 * 2);
    unsigned short* W2Tl = (unsigned short*)alloc((size_t)256 * 512 * 2);
    float* X1     = (float*)alloc((size_t)GG * 512 * 4);
    float* X2     = (float*)alloc((size_t)GG * 512 * 4);
    // aliases (stream-ordered, producer dead before reuse):
    float* H1P = (float*)A1h;                 // 32 MB: written after gemm1 consumed A1h
    float* H2  = (float*)A1l;                 // 32 MB: gemm2 out, after gemm1
    unsigned short* A2h = (unsigned short*)HG;                   // 32 MB of HG
    unsigned short* A2l = (unsigned short*)(HG + (size_t)NN0 * 128);  // next 32 MB

    hipMemsetAsync(STATS1, 0, 512 * sizeof(float), stream);
    hipMemsetAsync(STATS2, 0, 512 * sizeof(float), stream);
    hipMemsetAsync(MAP1, 0xFF, (size_t)NN0 * sizeof(int), stream);

    k_csr<<<GG, 512, 0, stream>>>(src, dst, ROWP, SSRC);
    k_w1t<<<256, 256, 0, stream>>>(W_rel1, W_root1, W1Th, W1Tl);
    k_w2t<<<512, 256, 0, stream>>>(W_rel2, W_root2, W2Th, W2Tl);
    k_q2norm<<<1, 256, 0, stream>>>(p2, Q2);
    k_copy_x<<<2048, 256, 0, stream>>>(x, A1h, A1l);
    k_agg1<<<8192, 256, 0, stream>>>(x, ROWP, SSRC, A1h, A1l);
    k_gemm3<256, 1><<<dim3(512, 2), 256, 0, stream>>>(A1h, A1l, W1Th, W1Tl, b_rel1, HG, STATS1, NN0);
    k_finalize1<<<1, 256, 0, stream>>>(STATS1, g1, bt1, p1, SCALE1, SHIFT1, Q1, R1);
    k_score<<<NN0 / 4, 256, 0, stream>>>(HG, Q1, R1, SCORES);
    k_topk<NPG, K1, 512><<<GG, 512, 0, stream>>>(SCORES, PERM1, VALS1, MAP1);
    k_pool1<<<GG, 256, 0, stream>>>(HG, PERM1, VALS1, SCALE1, SHIFT1, H1P, X1, STATS2);
    k_finalize2<<<1, 256, 0, stream>>>(STATS2, g2, bt2, SCALE2, SHIFT2);
    k_h2in<<<2048, 256, 0, stream>>>(H1P, SCALE2, SHIFT2, A2h, A2l, H2F);
    k_agg2<<<8192, 256, 0, stream>>>(H2F, ROWP, SSRC, PERM1, MAP1, A2h, A2l);
    k_gemm3<512, 0><<<dim3(256, 2), 256, 0, stream>>>(A2h, A2l, W2Th, W2Tl, b_rel2, H2, nullptr, NN1);
    k_score<<<NN1 / 4, 256, 0, stream>>>(H2, Q2, nullptr, SCORES);
    k_topk<K1, K2, 256><<<GG, 256, 0, stream>>>(SCORES, PERM2, VALS2, nullptr);
    k_x2<<<GG, 256, 0, stream>>>(H2, PERM2, VALS2, X2);
    k_final<<<GG, 256, 0, stream>>>(X1, X2, Wl, bl, out);
}

// Round 6
// 355.351 us; speedup vs baseline: 3.0034x; 1.1509x over previous
//
#include <hip/hip_runtime.h>
#include <hip/hip_bf16.h>
#include <float.h>

#define GG    64
#define NPG   1024
#define EPG   8192      // edges per graph
#define NE    524288
#define FIN   128
#define HID   256
#define K1    512
#define K2    256
#define NN0   65536     // GG*NPG
#define NN1   32768     // GG*K1
#define NN2   16384     // GG*K2
#define EPSBN 1e-5f

typedef short bf16x8 __attribute__((ext_vector_type(8)));
typedef float f32x4 __attribute__((ext_vector_type(4)));

__device__ __forceinline__ float gelu_exact(float v) {
    return 0.5f * v * (1.0f + erff(v * 0.7071067811865476f));
}

__device__ __forceinline__ unsigned short f2bf(float f) {
    union { float f; unsigned int u; } v; v.f = f;
    const unsigned int u = v.u;
    return (unsigned short)((u + 0x7FFFu + ((u >> 16) & 1u)) >> 16);   // RNE
}

__device__ __forceinline__ float bf2f(unsigned short h) {
    union { unsigned int u; float f; } v; v.u = ((unsigned int)h) << 16;
    return v.f;
}

// split fp32 -> hi/lo bf16 (hi + lo carries ~16 mantissa bits)
__device__ __forceinline__ void split_bf(float v, unsigned short& hi, unsigned short& lo) {
    hi = f2bf(v);
    lo = f2bf(v - bf2f(hi));
}

// ---------- weight transpose+concat to split-bf16 [N][K] ----------
__global__ __launch_bounds__(256) void k_w1t(const float* __restrict__ Wrel,
        const float* __restrict__ Wroot, unsigned short* __restrict__ WTh,
        unsigned short* __restrict__ WTl) {
    const int i = blockIdx.x * 256 + threadIdx.x;       // 65536 = 256n x 256k
    const int n = i >> 8, k = i & 255;
    const float v = (k < FIN) ? Wrel[k * HID + n] : Wroot[(k - FIN) * HID + n];
    unsigned short hi, lo; split_bf(v, hi, lo);
    WTh[i] = hi; WTl[i] = lo;
}

__global__ __launch_bounds__(256) void k_w2t(const float* __restrict__ Wrel,
        const float* __restrict__ Wroot, unsigned short* __restrict__ WTh,
        unsigned short* __restrict__ WTl) {
    const int i = blockIdx.x * 256 + threadIdx.x;       // 131072 = 256n x 512k
    const int n = i >> 9, k = i & 511;
    const float v = (k < HID) ? Wrel[k * HID + n] : Wroot[(k - HID) * HID + n];
    unsigned short hi, lo; split_bf(v, hi, lo);
    WTh[i] = hi; WTl[i] = lo;
}

__global__ __launch_bounds__(256) void k_q2norm(const float* __restrict__ p2,
        float* __restrict__ q2) {
    __shared__ float red[256];
    const int c = threadIdx.x;
    const float pv = p2[c];
    red[c] = pv * pv;
    __syncthreads();
    for (int s = 128; s > 0; s >>= 1) {
        if (c < s) red[c] += red[c + s];
        __syncthreads();
    }
    q2[c] = pv * rsqrtf(red[0]);
}

__global__ __launch_bounds__(256) void k_copy_x(const float* __restrict__ x,
        unsigned short* __restrict__ A1h, unsigned short* __restrict__ A1l) {
    const int total = NN0 * (FIN / 4);                  // float4 count
    for (int i = blockIdx.x * 256 + threadIdx.x; i < total; i += gridDim.x * 256) {
        const int r = i >> 5, c4 = i & 31;
        const float4 v = reinterpret_cast<const float4*>(x)[i];
        ushort4 h, l;
        split_bf(v.x, h.x, l.x); split_bf(v.y, h.y, l.y);
        split_bf(v.z, h.z, l.z); split_bf(v.w, h.w, l.w);
        const size_t o = (size_t)r * 256 + 128 + (c4 << 2);
        *reinterpret_cast<ushort4*>(&A1h[o]) = h;
        *reinterpret_cast<ushort4*>(&A1l[o]) = l;
    }
}

// ---------- CSR build: bucket edges by dst, one block per graph ----------
__global__ __launch_bounds__(512) void k_csr(const int* __restrict__ src,
        const int* __restrict__ dst, int* __restrict__ rowp,
        int* __restrict__ ssrc) {
    __shared__ int cnt[NPG];
    __shared__ int sa[NPG];
    __shared__ int sb[NPG];
    const int g = blockIdx.x, tid = threadIdx.x;
    const int eb = g * EPG;
    for (int i = tid; i < NPG; i += 512) cnt[i] = 0;
    __syncthreads();
    for (int e = tid; e < EPG; e += 512)
        atomicAdd(&cnt[dst[eb + e] & (NPG - 1)], 1);
    __syncthreads();
    for (int i = tid; i < NPG; i += 512) sa[i] = cnt[i];
    __syncthreads();
    int* cur = sa; int* nxt = sb;
    for (int d = 1; d < NPG; d <<= 1) {                 // inclusive scan
        for (int i = tid; i < NPG; i += 512)
            nxt[i] = cur[i] + ((i >= d) ? cur[i - d] : 0);
        __syncthreads();
        int* t = cur; cur = nxt; nxt = t;
    }
    for (int i = tid; i < NPG; i += 512) {
        const int st = cur[i] - cnt[i];                 // exclusive start
        rowp[g * (NPG + 1) + i] = st;
        cnt[i] = st;                                    // reuse as cursor
    }
    if (tid == 0) rowp[g * (NPG + 1) + NPG] = EPG;
    __syncthreads();
    for (int e = tid; e < EPG; e += 512) {
        const int d = dst[eb + e] & (NPG - 1);
        const int p = atomicAdd(&cnt[d], 1);
        ssrc[eb + p] = src[eb + e] & (NPG - 1);
    }
}

// ---------- agg1: CSR gather-sum, fp32 accumulate, split-bf16 out ----------
__global__ __launch_bounds__(256) void k_agg1(const float* __restrict__ x,
        const int* __restrict__ rowp, const int* __restrict__ ssrc,
        unsigned short* __restrict__ A1h, unsigned short* __restrict__ A1l) {
    const int b = blockIdx.x;
    const int g = b & 63;
    const int ng = b >> 6;                              // 0..127
    const int tid = threadIdx.x;
    const int ln = tid & 31;                            // col float4 0..31
    const int node = (ng << 3) + (tid >> 5);            // 0..1023
    const int s0 = rowp[g * (NPG + 1) + node];
    const int s1 = rowp[g * (NPG + 1) + node + 1];
    const float4* x4 = reinterpret_cast<const float4*>(x);
    const size_t gb = (size_t)(g << 10) * 32;           // 32 float4 per x row
    const int* sp = ssrc + (size_t)g * EPG;
    float4 acc = make_float4(0.f, 0.f, 0.f, 0.f);
    for (int j = s0; j < s1; ++j) {
        const float4 v = x4[gb + (size_t)sp[j] * 32 + ln];
        acc.x += v.x; acc.y += v.y; acc.z += v.z; acc.w += v.w;
    }
    ushort4 h, l;
    split_bf(acc.x, h.x, l.x); split_bf(acc.y, h.y, l.y);
    split_bf(acc.z, h.z, l.z); split_bf(acc.w, h.w, l.w);
    const size_t o = ((size_t)((g << 10) + node)) * 256 + (ln << 2);
    *reinterpret_cast<ushort4*>(&A1h[o]) = h;
    *reinterpret_cast<ushort4*>(&A1l[o]) = l;
}

// ---------- agg2: reuse layer-1 CSR buckets, fp32 in, split-bf16 out ----------
__global__ __launch_bounds__(256) void k_agg2(const float* __restrict__ H2F,
        const int* __restrict__ rowp, const int* __restrict__ ssrc,
        const int* __restrict__ perm1, const int* __restrict__ map1,
        unsigned short* __restrict__ A2h, unsigned short* __restrict__ A2l) {
    const int b = blockIdx.x;
    const int g = b & 63;
    const int ng = b >> 6;                              // 0..127
    const int tid = threadIdx.x;
    const int ln = tid & 63;                            // col float4 0..63
    const int ni = (ng << 2) + (tid >> 6);              // new node 0..511
    const int on = perm1[(g << 9) + ni] & (NPG - 1);    // old node id
    const int s0 = rowp[g * (NPG + 1) + on];
    const int s1 = rowp[g * (NPG + 1) + on + 1];
    const float4* h4 = reinterpret_cast<const float4*>(H2F);
    const int* sp = ssrc + (size_t)g * EPG;
    const int* mp = map1 + ((size_t)g << 10);
    float4 acc = make_float4(0.f, 0.f, 0.f, 0.f);
    for (int j = s0; j < s1; ++j) {
        const int ms = mp[sp[j]];                       // global new id or -1
        if (ms < 0) continue;                           // lane-uniform branch
        const float4 v = h4[(size_t)ms * 64 + ln];
        acc.x += v.x; acc.y += v.y; acc.z += v.z; acc.w += v.w;
    }
    ushort4 h, l;
    split_bf(acc.x, h.x, l.x); split_bf(acc.y, h.y, l.y);
    split_bf(acc.z, h.z, l.z); split_bf(acc.w, h.w, l.w);
    const size_t o = ((size_t)((g << 9) + ni)) * 512 + (ln << 2);
    *reinterpret_cast<ushort4*>(&A2h[o]) = h;
    *reinterpret_cast<ushort4*>(&A2l[o]) = l;
}

// ---------- split-bf16 MFMA GEMM, software-pipelined (issue-early prefetch) ----
// C[M][256] = (Ah+Al)[M][K] @ (Bh+Bl)[256][K]^T. 128x128 tile, 4 waves 2x2,
// each wave 64x64 = 4x4 frags of 16x16x32. acc += Ah*Bh + Ah*Bl + Al*Bh.
// EPI 0: +bias; 1: +bias, gelu, col sum/sumsq stats; 2: +bias, fused score-dot
template<int K, int EPI>
__global__ __launch_bounds__(256) void k_gemm3(
        const unsigned short* __restrict__ Ah, const unsigned short* __restrict__ Al,
        const unsigned short* __restrict__ Bh, const unsigned short* __restrict__ Bl,
        const float* __restrict__ bias, float* __restrict__ C,
        float* __restrict__ stats, const float* __restrict__ qv2,
        float* __restrict__ scores, int M) {
    constexpr int LK = 40;                              // 32 + 8 pad (80 B rows, 16B-aligned)
    __shared__ unsigned short Ash[128 * LK];
    __shared__ unsigned short Asl[128 * LK];
    __shared__ unsigned short Bsh[128 * LK];
    __shared__ unsigned short Bsl[128 * LK];
    __shared__ float csum[128];
    __shared__ float csq[128];
    const int tid = threadIdx.x;
    const int l = tid & 63, w = tid >> 6;
    const int wm = w >> 1, wn = w & 1;
    const int m0 = blockIdx.x * 128, n0 = blockIdx.y * 128;
    const int r16 = l & 15, kg = l >> 4;
    const int sr = tid >> 2, sco = (tid & 3) << 3;      // staging row, short-offset

    f32x4 acc[4][4] = {};

    // prologue prefetch (k0 = 0)
    uint4 pah0 = *reinterpret_cast<const uint4*>(Ah + (size_t)(m0 + sr) * K + sco);
    uint4 pah1 = *reinterpret_cast<const uint4*>(Ah + (size_t)(m0 + sr + 64) * K + sco);
    uint4 pal0 = *reinterpret_cast<const uint4*>(Al + (size_t)(m0 + sr) * K + sco);
    uint4 pal1 = *reinterpret_cast<const uint4*>(Al + (size_t)(m0 + sr + 64) * K + sco);
    uint4 pbh0 = *reinterpret_cast<const uint4*>(Bh + (size_t)(n0 + sr) * K + sco);
    uint4 pbh1 = *reinterpret_cast<const uint4*>(Bh + (size_t)(n0 + sr + 64) * K + sco);
    uint4 pbl0 = *reinterpret_cast<const uint4*>(Bl + (size_t)(n0 + sr) * K + sco);
    uint4 pbl1 = *reinterpret_cast<const uint4*>(Bl + (size_t)(n0 + sr + 64) * K + sco);

    for (int k0 = 0; k0 < K; k0 += 32) {
        __syncthreads();
        *reinterpret_cast<uint4*>(&Ash[sr * LK + sco]) = pah0;
        *reinterpret_cast<uint4*>(&Ash[(sr + 64) * LK + sco]) = pah1;
        *reinterpret_cast<uint4*>(&Asl[sr * LK + sco]) = pal0;
        *reinterpret_cast<uint4*>(&Asl[(sr + 64) * LK + sco]) = pal1;
        *reinterpret_cast<uint4*>(&Bsh[sr * LK + sco]) = pbh0;
        *reinterpret_cast<uint4*>(&Bsh[(sr + 64) * LK + sco]) = pbh1;
        *reinterpret_cast<uint4*>(&Bsl[sr * LK + sco]) = pbl0;
        *reinterpret_cast<uint4*>(&Bsl[(sr + 64) * LK + sco]) = pbl1;
        __syncthreads();
        if (k0 + 32 < K) {      // issue-early: next tile loads hide under MFMAs
            const int kn = k0 + 32;
            pah0 = *reinterpret_cast<const uint4*>(Ah + (size_t)(m0 + sr) * K + kn + sco);
            pah1 = *reinterpret_cast<const uint4*>(Ah + (size_t)(m0 + sr + 64) * K + kn + sco);
            pal0 = *reinterpret_cast<const uint4*>(Al + (size_t)(m0 + sr) * K + kn + sco);
            pal1 = *reinterpret_cast<const uint4*>(Al + (size_t)(m0 + sr + 64) * K + kn + sco);
            pbh0 = *reinterpret_cast<const uint4*>(Bh + (size_t)(n0 + sr) * K + kn + sco);
            pbh1 = *reinterpret_cast<const uint4*>(Bh + (size_t)(n0 + sr + 64) * K + kn + sco);
            pbl0 = *reinterpret_cast<const uint4*>(Bl + (size_t)(n0 + sr) * K + kn + sco);
            pbl1 = *reinterpret_cast<const uint4*>(Bl + (size_t)(n0 + sr + 64) * K + kn + sco);
        }
        bf16x8 afh[4], afl[4], bfh[4], bfl[4];
#pragma unroll
        for (int mi = 0; mi < 4; ++mi) {
            const int ro = (wm * 64 + mi * 16 + r16) * LK + (kg << 3);
            afh[mi] = *reinterpret_cast<const bf16x8*>(&Ash[ro]);
            afl[mi] = *reinterpret_cast<const bf16x8*>(&Asl[ro]);
        }
#pragma unroll
        for (int ni = 0; ni < 4; ++ni) {
            const int ro = (wn * 64 + ni * 16 + r16) * LK + (kg << 3);
            bfh[ni] = *reinterpret_cast<const bf16x8*>(&Bsh[ro]);
            bfl[ni] = *reinterpret_cast<const bf16x8*>(&Bsl[ro]);
        }
#pragma unroll
        for (int mi = 0; mi < 4; ++mi)
#pragma unroll
            for (int ni = 0; ni < 4; ++ni) {
                acc[mi][ni] = __builtin_amdgcn_mfma_f32_16x16x32_bf16(
                    afh[mi], bfh[ni], acc[mi][ni], 0, 0, 0);
                acc[mi][ni] = __builtin_amdgcn_mfma_f32_16x16x32_bf16(
                    afh[mi], bfl[ni], acc[mi][ni], 0, 0, 0);
                acc[mi][ni] = __builtin_amdgcn_mfma_f32_16x16x32_bf16(
                    afl[mi], bfh[ni], acc[mi][ni], 0, 0, 0);
            }
    }

    if (EPI == 1) {
        if (tid < 128) { csum[tid] = 0.f; csq[tid] = 0.f; }
        __syncthreads();
    }

    float qv[4];
    if (EPI == 2) {
#pragma unroll
        for (int ni = 0; ni < 4; ++ni) qv[ni] = qv2[n0 + wn * 64 + ni * 16 + r16];
    }
    float sA[4] = {0, 0, 0, 0};
    float qA[4] = {0, 0, 0, 0};
    float sp[4][4] = {};
#pragma unroll
    for (int mi = 0; mi < 4; ++mi)
#pragma unroll
        for (int ni = 0; ni < 4; ++ni) {
            const int col = n0 + wn * 64 + ni * 16 + r16;
            const float bc = bias[col];
#pragma unroll
            for (int r = 0; r < 4; ++r) {
                const int row = m0 + wm * 64 + mi * 16 + (kg << 2) + r;
                float t = acc[mi][ni][r] + bc;
                if (EPI == 1) {
                    t = gelu_exact(t);
                    sA[ni] += t;
                    qA[ni] += t * t;
                }
                if (EPI == 2) sp[mi][r] += t * qv[ni];
                C[(size_t)row * 256 + col] = t;
            }
        }
    if (EPI == 1) {
#pragma unroll
        for (int ni = 0; ni < 4; ++ni) {
            const int cl = wn * 64 + ni * 16 + r16;
            unsafeAtomicAdd(&csum[cl], sA[ni]);
            unsafeAtomicAdd(&csq[cl], qA[ni]);
        }
        __syncthreads();
        if (tid < 128) {
            unsafeAtomicAdd(&stats[n0 + tid], csum[tid]);
            unsafeAtomicAdd(&stats[HID + n0 + tid], csq[tid]);
        }
    }
    if (EPI == 2) {
#pragma unroll
        for (int mi = 0; mi < 4; ++mi)
#pragma unroll
            for (int r = 0; r < 4; ++r) {
                float s = sp[mi][r];
                s += __shfl_xor(s, 1);
                s += __shfl_xor(s, 2);
                s += __shfl_xor(s, 4);
                s += __shfl_xor(s, 8);
                if (r16 == 0)
                    atomicAdd(&scores[m0 + wm * 64 + mi * 16 + (kg << 2) + r], s);
            }
    }
}

// ---------- BN finalize / score fold ----------
__global__ __launch_bounds__(256) void k_finalize1(const float* __restrict__ stats,
        const float* __restrict__ g1, const float* __restrict__ bt1,
        const float* __restrict__ p1, float* __restrict__ scale,
        float* __restrict__ shift, float* __restrict__ q, float* __restrict__ r) {
    __shared__ float red[256];
    const int c = threadIdx.x;
    const float m = stats[c] * (1.f / NN0);
    const float v = stats[HID + c] * (1.f / NN0) - m * m;
    const float sc = g1[c] * rsqrtf(v + EPSBN);
    const float sh = bt1[c] - m * sc;
    scale[c] = sc;
    shift[c] = sh;
    const float pv = p1[c];
    red[c] = pv * pv;
    __syncthreads();
    for (int s = 128; s > 0; s >>= 1) {
        if (c < s) red[c] += red[c + s];
        __syncthreads();
    }
    const float inv = rsqrtf(red[0]);
    q[c] = sc * pv * inv;
    __syncthreads();
    red[c] = sh * pv * inv;
    __syncthreads();
    for (int s = 128; s > 0; s >>= 1) {
        if (c < s) red[c] += red[c + s];
        __syncthreads();
    }
    if (c == 0) r[0] = red[0];
}

__global__ __launch_bounds__(256) void k_finalize2(const float* __restrict__ stats,
        const float* __restrict__ g2, const float* __restrict__ bt2,
        float* __restrict__ scale, float* __restrict__ shift) {
    const int c = threadIdx.x;
    const float m = stats[c] * (1.f / NN1);
    const float v = stats[HID + c] * (1.f / NN1) - m * m;
    const float sc = g2[c] * rsqrtf(v + EPSBN);
    scale[c] = sc;
    shift[c] = bt2[c] - m * sc;
}

// ---------- scores (layer1): raw dot h.q + r (tanh applied in topk) ----------
__global__ __launch_bounds__(256) void k_score(const float* __restrict__ H,
        const float* __restrict__ q, const float* __restrict__ r,
        float* __restrict__ out) {
    const int node = blockIdx.x * 4 + (threadIdx.x >> 6);
    const int lane = threadIdx.x & 63;
    const float4 h = *reinterpret_cast<const float4*>(H + (size_t)node * HID + (lane << 2));
    const float4 qv = *reinterpret_cast<const float4*>(q + (lane << 2));
    float d = h.x * qv.x + h.y * qv.y + h.z * qv.z + h.w * qv.w;
#pragma unroll
    for (int off = 32; off > 0; off >>= 1) d += __shfl_xor(d, off);
    if (lane == 0) out[node] = d + (r ? r[0] : 0.f);
}

// ---------- per-graph bitonic top-k (applies tanh at load) ----------
template<int NN_, int KK_, int NT_>
__global__ __launch_bounds__(NT_) void k_topk(const float* __restrict__ scores,
        int* __restrict__ perm, float* __restrict__ vals, int* __restrict__ mapping) {
    __shared__ float s[NN_];
    __shared__ int id[NN_];
    const int g = blockIdx.x, tid = threadIdx.x;
    for (int i = tid; i < NN_; i += NT_) { s[i] = tanhf(scores[g * NN_ + i]); id[i] = i; }
    __syncthreads();
    for (int k = 2; k <= NN_; k <<= 1) {
        for (int j = k >> 1; j > 0; j >>= 1) {
            for (int t = tid; t < NN_; t += NT_) {
                const int ixj = t ^ j;
                if (ixj > t) {
                    const bool desc = ((t & k) == 0);
                    const float s1 = s[t], s2 = s[ixj];
                    const int i1 = id[t], i2 = id[ixj];
                    const bool inOrder = (s1 > s2) || (s1 == s2 && i1 < i2);
                    if (inOrder != desc) { s[t] = s2; s[ixj] = s1; id[t] = i2; id[ixj] = i1; }
                }
            }
            __syncthreads();
        }
    }
    for (int i = tid; i < KK_; i += NT_) {
        const int oid = id[i];
        perm[g * KK_ + i] = g * NN_ + oid;
        vals[g * KK_ + i] = s[i];
        if (mapping) mapping[g * NN_ + oid] = g * KK_ + i;
    }
}

// ---------- pool1 apply, stage 1: 512 blocks (g x 8 node-groups) ----------
__global__ __launch_bounds__(256) void k_pool1p(const float* __restrict__ HG,
        const int* __restrict__ perm, const float* __restrict__ vals,
        const float* __restrict__ scale1, const float* __restrict__ shift1,
        float* __restrict__ H1P, float* __restrict__ pmax,
        float* __restrict__ psum, float* __restrict__ psq) {
    const int b = blockIdx.x;
    const int g = b >> 3, ig = b & 7;
    const int c = threadIdx.x;
    const float sc = scale1[c], sh = shift1[c];
    float mx = -FLT_MAX, sm = 0.f, sq = 0.f;
    for (int i = ig * 64; i < ig * 64 + 64; ++i) {
        const int idx = (g << 9) + i;
        const int srow = perm[idx];
        const float val = vals[idx];
        const float hv = HG[(size_t)srow * HID + c];
        const float xn = (hv * sc + sh) * val;
        H1P[(size_t)idx * HID + c] = xn;
        mx = fmaxf(mx, xn);
        sm += xn;
        sq += xn * xn;
    }
    pmax[b * 256 + c] = mx;
    psum[b * 256 + c] = sm;
    psq[b * 256 + c] = sq;
}

// ---------- pool1 stage 2: reduce 8 partials, x1 readout, bn2 stats ----------
__global__ __launch_bounds__(256) void k_pool1r(const float* __restrict__ pmax,
        const float* __restrict__ psum, const float* __restrict__ psq,
        float* __restrict__ X1, float* __restrict__ stats2) {
    const int g = blockIdx.x, c = threadIdx.x;
    float mx = -FLT_MAX, sm = 0.f, sq = 0.f;
    for (int ig = 0; ig < 8; ++ig) {
        const int o = ((g << 3) + ig) * 256 + c;
        mx = fmaxf(mx, pmax[o]);
        sm += psum[o];
        sq += psq[o];
    }
    X1[g * 512 + c] = mx;
    X1[g * 512 + 256 + c] = sm * (1.f / K1);
    unsafeAtomicAdd(&stats2[c], sm);
    unsafeAtomicAdd(&stats2[HID + c], sq);
}

// ---------- h2in = gelu(bn2(h1p)): fp32 copy + split-bf16 A2 right half ----------
__global__ __launch_bounds__(256) void k_h2in(const float* __restrict__ H1P,
        const float* __restrict__ scale2, const float* __restrict__ shift2,
        unsigned short* __restrict__ A2h, unsigned short* __restrict__ A2l,
        float* __restrict__ H2F) {
    const int total = NN1 * (HID / 4);
    for (int i = blockIdx.x * 256 + threadIdx.x; i < total; i += gridDim.x * 256) {
        const int r = i >> 6, c4 = i & 63;
        const float4 v = reinterpret_cast<const float4*>(H1P)[i];
        const float4 sc = reinterpret_cast<const float4*>(scale2)[c4];
        const float4 sh = reinterpret_cast<const float4*>(shift2)[c4];
        float4 o;
        o.x = gelu_exact(v.x * sc.x + sh.x);
        o.y = gelu_exact(v.y * sc.y + sh.y);
        o.z = gelu_exact(v.z * sc.z + sh.z);
        o.w = gelu_exact(v.w * sc.w + sh.w);
        reinterpret_cast<float4*>(H2F)[i] = o;
        ushort4 h, l;
        split_bf(o.x, h.x, l.x); split_bf(o.y, h.y, l.y);
        split_bf(o.z, h.z, l.z); split_bf(o.w, h.w, l.w);
        const size_t off = (size_t)r * 512 + 256 + (c4 << 2);
        *reinterpret_cast<ushort4*>(&A2h[off]) = h;
        *reinterpret_cast<ushort4*>(&A2l[off]) = l;
    }
}

// ---------- x2 readout ----------
__global__ __launch_bounds__(256) void k_x2(const float* __restrict__ H2,
        const int* __restrict__ perm, const float* __restrict__ vals,
        float* __restrict__ X2) {
    const int g = blockIdx.x, c = threadIdx.x;
    float mx = -FLT_MAX, sm = 0.f;
    for (int i = 0; i < K2; ++i) {
        const int idx = g * K2 + i;
        const int srow = perm[idx];
        const float v = H2[(size_t)srow * HID + c] * vals[idx];
        mx = fmaxf(mx, v);
        sm += v;
    }
    X2[g * 512 + c] = mx;
    X2[g * 512 + 256 + c] = sm * (1.f / K2);
}

// ---------- final linear: out = (x1+x2) @ Wl + bl ----------
__global__ __launch_bounds__(256) void k_final(const float* __restrict__ X1,
        const float* __restrict__ X2, const float* __restrict__ Wl,
        const float* __restrict__ bl, float* __restrict__ out) {
    const int g = blockIdx.x, c = threadIdx.x;
    float acc = bl[c];
    for (int k = 0; k < 512; ++k) {
        const float xv = X1[g * 512 + k] + X2[g * 512 + k];
        acc = fmaf(xv, Wl[k * HID + c], acc);
    }
    out[g * HID + c] = acc;
}

extern "C" void kernel_launch(void* const* d_in, const int* in_sizes, int n_in,
                              void* d_out, int out_size, void* d_ws, size_t ws_size,
                              hipStream_t stream) {
    (void)in_sizes; (void)n_in; (void)out_size; (void)ws_size;
    const float* x       = (const float*)d_in[0];
    const int*   src     = (const int*)  d_in[1];
    const int*   dst     = (const int*)  d_in[2];
    const float* W_rel1  = (const float*)d_in[3];
    const float* b_rel1  = (const float*)d_in[4];
    const float* W_root1 = (const float*)d_in[5];
    const float* g1      = (const float*)d_in[6];
    const float* bt1     = (const float*)d_in[7];
    const float* p1      = (const float*)d_in[8];
    const float* g2      = (const float*)d_in[9];
    const float* bt2     = (const float*)d_in[10];
    const float* W_rel2  = (const float*)d_in[11];
    const float* b_rel2  = (const float*)d_in[12];
    const float* W_root2 = (const float*)d_in[13];
    const float* p2      = (const float*)d_in[14];
    const float* Wl      = (const float*)d_in[15];
    const float* bl      = (const float*)d_in[16];
    float* out = (float*)d_out;

    char* w = (char*)d_ws;
    size_t off = 0;
    auto alloc = [&](size_t bytes) -> void* {
        void* p = w + off;
        off += (bytes + 255) & ~(size_t)255;
        return p;
    };
    unsigned short* A1h = (unsigned short*)alloc((size_t)NN0 * 256 * 2);  // 32 MB
    unsigned short* A1l = (unsigned short*)alloc((size_t)NN0 * 256 * 2);  // 32 MB
    float* HG     = (float*)alloc((size_t)NN0 * 256 * 4);   // 64 MB: gelu(conv1) fp32
    float* H2F    = (float*)alloc((size_t)NN1 * 256 * 4);   // 32 MB: gelu(bn2) fp32
    int*   ROWP   = (int*)  alloc((size_t)GG * (NPG + 1) * 4);
    int*   SSRC   = (int*)  alloc((size_t)NE * 4);
    float* SCORES = (float*)alloc((size_t)NN0 * 4);         // reused for pool2
    int*   PERM1  = (int*)  alloc((size_t)NN1 * 4);
    float* VALS1  = (float*)alloc((size_t)NN1 * 4);
    int*   MAP1   = (int*)  alloc((size_t)NN0 * 4);
    int*   PERM2  = (int*)  alloc((size_t)NN2 * 4);
    float* VALS2  = (float*)alloc((size_t)NN2 * 4);
    float* STATS1 = (float*)alloc(512 * 4);
    float* STATS2 = (float*)alloc(512 * 4);
    float* SCALE1 = (float*)alloc(256 * 4);
    float* SHIFT1 = (float*)alloc(256 * 4);
    float* Q1     = (float*)alloc(256 * 4);
    float* R1     = (float*)alloc(256);
    float* SCALE2 = (float*)alloc(256 * 4);
    float* SHIFT2 = (float*)alloc(256 * 4);
    float* Q2     = (float*)alloc(256 * 4);
    unsigned short* W1Th = (unsigned short*)alloc((size_t)256 * 256 * 2);
    unsigned short* W1Tl = (unsigned short*)alloc((size_t)256 * 256 * 2);
    unsigned short* W2Th = (unsigned short*)alloc((size_t)256 * 512 * 2);
    unsigned short* W2Tl = (unsigned short*)alloc((size_t)256 * 512 * 2);
    float* X1     = (float*)alloc((size_t)GG * 512 * 4);
    float* X2     = (float*)alloc((size_t)GG * 512 * 4);
    float* PMAX   = (float*)alloc((size_t)512 * 256 * 4);
    float* PSUM   = (float*)alloc((size_t)512 * 256 * 4);
    float* PSQ    = (float*)alloc((size_t)512 * 256 * 4);
    // aliases (stream-ordered, producer dead before reuse):
    float* H1P = (float*)A1h;                 // 32 MB: written after gemm1 consumed A1h
    float* H2  = (float*)A1l;                 // 32 MB: gemm2 out, after gemm1
    unsigned short* A2h = (unsigned short*)HG;                   // 32 MB of HG
    unsigned short* A2l = (unsigned short*)(HG + (size_t)NN0 * 128);  // next 32 MB

    hipMemsetAsync(STATS1, 0, 512 * sizeof(float), stream);
    hipMemsetAsync(STATS2, 0, 512 * sizeof(float), stream);
    hipMemsetAsync(MAP1, 0xFF, (size_t)NN0 * sizeof(int), stream);

    k_csr<<<GG, 512, 0, stream>>>(src, dst, ROWP, SSRC);
    k_w1t<<<256, 256, 0, stream>>>(W_rel1, W_root1, W1Th, W1Tl);
    k_w2t<<<512, 256, 0, stream>>>(W_rel2, W_root2, W2Th, W2Tl);
    k_q2norm<<<1, 256, 0, stream>>>(p2, Q2);
    k_copy_x<<<2048, 256, 0, stream>>>(x, A1h, A1l);
    k_agg1<<<8192, 256, 0, stream>>>(x, ROWP, SSRC, A1h, A1l);
    k_gemm3<256, 1><<<dim3(512, 2), 256, 0, stream>>>(A1h, A1l, W1Th, W1Tl,
        b_rel1, HG, STATS1, nullptr, nullptr, NN0);
    k_finalize1<<<1, 256, 0, stream>>>(STATS1, g1, bt1, p1, SCALE1, SHIFT1, Q1, R1);
    k_score<<<NN0 / 4, 256, 0, stream>>>(HG, Q1, R1, SCORES);
    k_topk<NPG, K1, 512><<<GG, 512, 0, stream>>>(SCORES, PERM1, VALS1, MAP1);
    k_pool1p<<<512, 256, 0, stream>>>(HG, PERM1, VALS1, SCALE1, SHIFT1, H1P, PMAX, PSUM, PSQ);
    k_pool1r<<<GG, 256, 0, stream>>>(PMAX, PSUM, PSQ, X1, STATS2);
    k_finalize2<<<1, 256, 0, stream>>>(STATS2, g2, bt2, SCALE2, SHIFT2);
    k_h2in<<<2048, 256, 0, stream>>>(H1P, SCALE2, SHIFT2, A2h, A2l, H2F);
    k_agg2<<<8192, 256, 0, stream>>>(H2F, ROWP, SSRC, PERM1, MAP1, A2h, A2l);
    hipMemsetAsync(SCORES, 0, (size_t)NN1 * sizeof(float), stream);
    k_gemm3<512, 2><<<dim3(256, 2), 256, 0, stream>>>(A2h, A2l, W2Th, W2Tl,
        b_rel2, H2, nullptr, Q2, SCORES, NN1);
    k_topk<K1, K2, 256><<<GG, 256, 0, stream>>>(SCORES, PERM2, VALS2, nullptr);
    k_x2<<<GG, 256, 0, stream>>>(H2, PERM2, VALS2, X2);
    k_final<<<GG, 256, 0, stream>>>(X1, X2, Wl, bl, out);
}